// Round 1
// 3071.562 us; speedup vs baseline: 1.0045x; 1.0045x over previous
//
#include <hip/hip_runtime.h>

#define BB 64
#define HH 256
#define LC 2048
#define LQ 256
#define NEGV -1e30f

// ---- legacy (fp32 MODE0) workspace layout in floats ----
#define OFF_S    0L
#define OFF_PM   33554432L            // B*LC*LQ
#define OFF_PL   33685504L            // + B*8*LQ
#define OFF_T    33816576L            // + B*8*LQ
#define OFF_FLAG 38010880L            // + B*H*LQ

// ---- new (bf16 MODE1) workspace layout in floats ----
// Bfold (u16, B*LQ*2*HH = 8388608 u16 = 4194304 f) lives at 33554432..37748736.
// It is DEAD after nk1; NPM/NPL/T alias over it afterwards (stream-ordered).
#define NOFF_BF  33554432L
#define NOFF_Q2  37748736L            // B*LQ floats (dead after nk1)
#define NOFF_PM  33554432L            // B*16*LQ floats (written by nk2a, after BF dead)
#define NOFF_PL  33816576L
#define NOFF_T   34078720L            // u16 Tt[b][h][j], B*H*LQ u16 = 2097152 f

typedef __attribute__((ext_vector_type(8))) short short8v;   // 8 bf16 (4 VGPRs)
typedef __attribute__((ext_vector_type(4))) float f32x4;

union FragU { uint4 u; short8v h; };

__device__ __forceinline__ short8v ldfrag(const unsigned short* p) {
  FragU f; f.u = *reinterpret_cast<const uint4*>(p); return f.h;
}

#define MFMA(a, b, c) __builtin_amdgcn_mfma_f32_16x16x32_bf16(a, b, c, 0, 0, 0)

template<int MODE>
__device__ __forceinline__ float ld(const void* p, long idx) {
  if (MODE == 1) {
    unsigned short u = ((const unsigned short*)p)[idx];
    return __uint_as_float(((unsigned int)u) << 16);
  } else {
    return ((const float*)p)[idx];
  }
}

__device__ __forceinline__ float bf2f(unsigned short u) {
  return __uint_as_float(((unsigned int)u) << 16);
}

__device__ __forceinline__ unsigned short f2bf(float f) {
  unsigned int u = __float_as_uint(f);
  unsigned int r = (u + 0x7fffu + ((u >> 16) & 1u)) >> 16;
  return (unsigned short)r;
}

union U16x8 { uint4 u; unsigned short s[8]; };

// ---------------- dtype sniff ----------------
__global__ void sniff_kernel(const unsigned int* cw, int* flag) {
  __shared__ int cnt[64];
  int tid = threadIdx.x;
  unsigned int w = cw[tid];
  int p = 0;
  for (int h = 0; h < 2; h++) {
    unsigned short u = h ? (unsigned short)(w >> 16) : (unsigned short)(w & 0xffffu);
    float f = __uint_as_float(((unsigned int)u) << 16);
    float a = fabsf(f);
    if ((a >= 1e-5f && a <= 64.0f) || f == 0.0f) p++;
  }
  cnt[tid] = p;
  __syncthreads();
  if (tid == 0) {
    int t = 0;
    for (int i = 0; i < 64; i++) t += cnt[i];
    *flag = (t >= 102) ? 1 : 0;   // 1 = bf16 I/O, 0 = fp32 I/O
  }
}

// =====================================================================
// ==================== NEW bf16 MFMA pipeline (MODE 1) ================
// =====================================================================

// nk0: Bfold[b][j][{hi,lo}][h] = split_bf16(w1[h] + w3[h]*Q[h,j]);  q2[b][j]
__global__ __launch_bounds__(256) void nk0_bfold(const void* Qp, const void* lpp,
                                                 float* ws, const int* flag) {
  if (*flag != 1) return;
  __shared__ __align__(16) unsigned short Qs[64 * 72];
  __shared__ float w1s[HH], w2s[HH], w3s[HH];
  __shared__ float q2red[4][64];
  int t = threadIdx.x;
  int b = blockIdx.y, j0 = blockIdx.x * 64;
  w1s[t] = ld<1>(lpp, t);
  w2s[t] = ld<1>(lpp, HH + t);
  w3s[t] = ld<1>(lpp, 2 * HH + t);
  const unsigned short* Qu = (const unsigned short*)Qp;
  long qbase = (long)b * HH * LQ;
  unsigned short* Bf = (unsigned short*)(ws + NOFF_BF);
  int jl = t & 63, hg = t >> 6;
  float q2a = 0.f;
  for (int hp = 0; hp < 4; hp++) {
    int h0 = hp * 64;
    __syncthreads();
    {
      int row = t >> 2, c = t & 3;
      const uint4* src = (const uint4*)&Qu[qbase + (long)(h0 + row) * LQ + j0 + c * 16];
      uint4 v0 = src[0]; uint4 v1 = src[1];
      *(uint4*)&Qs[row * 72 + c * 16] = v0;
      *(uint4*)&Qs[row * 72 + c * 16 + 8] = v1;
    }
    __syncthreads();
    unsigned int hiw[8], low[8];
#pragma unroll
    for (int e = 0; e < 16; e++) {
      int hh = hg * 16 + e;
      int h = h0 + hh;
      float qv = bf2f(Qs[hh * 72 + jl]);
      float bb = w1s[h] + w3s[h] * qv;
      q2a += w2s[h] * qv;
      unsigned short bh = f2bf(bb);
      float res = bb - bf2f(bh);
      unsigned short bl = f2bf(res);
      if (e & 1) { hiw[e >> 1] |= ((unsigned int)bh) << 16; low[e >> 1] |= ((unsigned int)bl) << 16; }
      else       { hiw[e >> 1] = bh; low[e >> 1] = bl; }
    }
    long bfb = ((long)b * LQ + j0 + jl) * (2 * HH);
    *(uint4*)&Bf[bfb + h0 + hg * 16]      = make_uint4(hiw[0], hiw[1], hiw[2], hiw[3]);
    *(uint4*)&Bf[bfb + h0 + hg * 16 + 8]  = make_uint4(hiw[4], hiw[5], hiw[6], hiw[7]);
    *(uint4*)&Bf[bfb + HH + h0 + hg * 16]     = make_uint4(low[0], low[1], low[2], low[3]);
    *(uint4*)&Bf[bfb + HH + h0 + hg * 16 + 8] = make_uint4(low[4], low[5], low[6], low[7]);
  }
  q2red[hg][jl] = q2a;
  __syncthreads();
  if (t < 64)
    ws[NOFF_Q2 + (long)b * LQ + j0 + t] =
        q2red[0][t] + q2red[1][t] + q2red[2][t] + q2red[3][t];
}

// nk1: S[i,j] = sum_h C[h,i]*(w1+w3*Q)[j,h] + q2[j]   via MFMA, fp32 S to ws
__global__ __launch_bounds__(256) void nk1_S(const void* Cp, float* ws, const int* flag) {
  if (*flag != 1) return;
  __shared__ __align__(16) unsigned short Ca[64 * 40];   // [i][h] pitch 40 u16 (80B, 16B-aligned)
  int t = threadIdx.x;
  int b = blockIdx.y, i0 = blockIdx.x * 64;
  int w = t >> 6, l = t & 63;
  int lane_m = l & 15, kb = l >> 4;
  const unsigned short* Cu = (const unsigned short*)Cp;
  const unsigned short* Bf = (const unsigned short*)(ws + NOFF_BF);
  long cbase = (long)b * HH * LC;
  f32x4 z4 = {0.f, 0.f, 0.f, 0.f};
  f32x4 acc[4][4];
#pragma unroll
  for (int mf = 0; mf < 4; mf++)
#pragma unroll
    for (int nf = 0; nf < 4; nf++) acc[mf][nf] = z4;

  for (int hc = 0; hc < 8; hc++) {
    int h0 = hc * 32;
    __syncthreads();
#pragma unroll
    for (int hp = 0; hp < 4; hp++) {   // transpose-stage C tile [64 i][32 h]
      int hh = hp * 8 + (t >> 5);
      int ii = (t & 31) * 2;
      unsigned int cw = *(const unsigned int*)&Cu[cbase + (long)(h0 + hh) * LC + i0 + ii];
      Ca[ii * 40 + hh] = (unsigned short)(cw & 0xffffu);
      Ca[(ii + 1) * 40 + hh] = (unsigned short)(cw >> 16);
    }
    __syncthreads();
    short8v afr[4];
#pragma unroll
    for (int mf = 0; mf < 4; mf++)
      afr[mf] = ldfrag(&Ca[(mf * 16 + lane_m) * 40 + kb * 8]);
#pragma unroll
    for (int nf = 0; nf < 4; nf++) {
      long jb = ((long)b * LQ + w * 64 + nf * 16 + lane_m) * (2 * HH) + h0 + kb * 8;
      short8v bh = ldfrag(&Bf[jb]);
      short8v bl = ldfrag(&Bf[jb + HH]);
#pragma unroll
      for (int mf = 0; mf < 4; mf++) {
        acc[mf][nf] = MFMA(afr[mf], bh, acc[mf][nf]);
        acc[mf][nf] = MFMA(afr[mf], bl, acc[mf][nf]);
      }
    }
  }
  const float* q2g = ws + NOFF_Q2 + (long)b * LQ;
#pragma unroll
  for (int nf = 0; nf < 4; nf++) {
    int j = w * 64 + nf * 16 + lane_m;
    float q2v = q2g[j];
    float* So = ws + OFF_S + ((long)b * LC + i0 + kb * 4) * LQ + j;
#pragma unroll
    for (int mf = 0; mf < 4; mf++)
#pragma unroll
      for (int r = 0; r < 4; r++)
        So[(long)(mf * 16 + r) * LQ] = acc[mf][nf][r] + q2v;
  }
}

// nk2a: column-softmax partials over 16 i-chunks of 128 (two-pass, L2-hot)
__global__ __launch_bounds__(256) void nk2a_col(const void* cmaskp, float* ws, const int* flag) {
  if (*flag != 1) return;
  __shared__ float cms[128];
  int t = threadIdx.x, ch = blockIdx.x, b = blockIdx.y;
  int ib = ch * 128;
  if (t < 128) cms[t] = ld<1>(cmaskp, (long)b * LC + ib + t);
  __syncthreads();
  const float* Sb = ws + OFF_S + ((long)b * LC + ib) * LQ + t;
  float m = -INFINITY;
#pragma unroll 8
  for (int i = 0; i < 128; i++) {
    float v = (cms[i] != 0.f) ? NEGV : Sb[(long)i * LQ];
    m = fmaxf(m, v);
  }
  float s = 0.f;
#pragma unroll 8
  for (int i = 0; i < 128; i++) {
    float v = (cms[i] != 0.f) ? NEGV : Sb[(long)i * LQ];
    s += __expf(v - m);
  }
  ws[NOFF_PM + ((long)b * 16 + ch) * LQ + t] = m;
  ws[NOFF_PL + ((long)b * 16 + ch) * LQ + t] = s;
}

// nk2b: Tt[b][h][j] = sum_i Pc[i,j]*C[h,i]  via MFMA, bf16 output
__global__ __launch_bounds__(512) void nk2b_T(const void* Cp, const void* cmaskp,
                                              float* ws, const int* flag) {
  if (*flag != 1) return;
  __shared__ __align__(16) unsigned short Pt[64 * 72];   // [j][i] pitch 72 u16
  int t = threadIdx.x, b = blockIdx.y, j0 = blockIdx.x * 64;
  int w = t >> 6, l = t & 63;
  int lane_m = l & 15, kb = l >> 4;
  int jj = j0 + l;
  float M = -INFINITY;
#pragma unroll
  for (int c = 0; c < 16; c++)
    M = fmaxf(M, ws[NOFF_PM + ((long)b * 16 + c) * LQ + jj]);
  float L = 0.f;
#pragma unroll
  for (int c = 0; c < 16; c++)
    L += ws[NOFF_PL + ((long)b * 16 + c) * LQ + jj] *
         __expf(ws[NOFF_PM + ((long)b * 16 + c) * LQ + jj] - M);
  float Li = 1.0f / L;
  int hw = (w >> 1) * 64, jw = (w & 1) * 32;
  const unsigned short* Cu = (const unsigned short*)Cp;
  long cbase = (long)b * HH * LC;
  const float* Sb = ws + OFF_S + (long)b * LC * LQ;
  f32x4 z4 = {0.f, 0.f, 0.f, 0.f};
  f32x4 acc[4][2];
#pragma unroll
  for (int mf = 0; mf < 4; mf++) { acc[mf][0] = z4; acc[mf][1] = z4; }

  for (int ic = 0; ic < 32; ic++) {
    int i0 = ic * 64;
    __syncthreads();
    unsigned int pw[4];
#pragma unroll
    for (int s2 = 0; s2 < 4; s2++) {
      unsigned int lo16, hi16;
      {
        int i = i0 + w * 8 + 2 * s2;
        float cm = ld<1>(cmaskp, (long)b * LC + i);
        float sv = Sb[(long)i * LQ + jj];
        float p = (cm != 0.f) ? 0.f : __expf(sv - M) * Li;
        lo16 = f2bf(p);
      }
      {
        int i = i0 + w * 8 + 2 * s2 + 1;
        float cm = ld<1>(cmaskp, (long)b * LC + i);
        float sv = Sb[(long)i * LQ + jj];
        float p = (cm != 0.f) ? 0.f : __expf(sv - M) * Li;
        hi16 = f2bf(p);
      }
      pw[s2] = lo16 | (hi16 << 16);
    }
    *(uint4*)&Pt[l * 72 + w * 8] = make_uint4(pw[0], pw[1], pw[2], pw[3]);
    __syncthreads();
#pragma unroll
    for (int ks = 0; ks < 2; ks++) {
      short8v b0 = ldfrag(&Pt[(jw + lane_m) * 72 + ks * 32 + kb * 8]);
      short8v b1 = ldfrag(&Pt[(jw + 16 + lane_m) * 72 + ks * 32 + kb * 8]);
#pragma unroll
      for (int mf = 0; mf < 4; mf++) {
        short8v a = ldfrag(&Cu[cbase + (long)(hw + mf * 16 + lane_m) * LC + i0 + ks * 32 + kb * 8]);
        acc[mf][0] = MFMA(a, b0, acc[mf][0]);
        acc[mf][1] = MFMA(a, b1, acc[mf][1]);
      }
    }
  }
  unsigned short* Tt = (unsigned short*)(ws + NOFF_T);
#pragma unroll
  for (int mf = 0; mf < 4; mf++)
#pragma unroll
    for (int nf = 0; nf < 2; nf++)
#pragma unroll
      for (int r = 0; r < 4; r++) {
        int h = hw + mf * 16 + kb * 4 + r;
        int j = j0 + jw + nf * 16 + lane_m;
        Tt[((long)b * HH + h) * LQ + j] = f2bf(acc[mf][nf][r]);
      }
}

// nk3: row softmax -> Pr bf16 in LDS -> A=Pr@Qt^T and Bt=Pr@Tt^T via MFMA -> fused out
__global__ __launch_bounds__(512) void nk3_out(const void* Cp, const void* Qp, const void* qmaskp,
                                               float* ws, void* outp, const int* flag) {
  if (*flag != 1) return;
  __shared__ __align__(16) unsigned short Pr[64 * 264];  // [i][j] pitch 264 u16
  __shared__ float qms[LQ];
  int t = threadIdx.x, b = blockIdx.y, i0 = blockIdx.x * 64;
  int w = t >> 6, l = t & 63;
  if (t < LQ) qms[t] = ld<1>(qmaskp, (long)b * LQ + t);
  __syncthreads();
  const float* Sb = ws + OFF_S + ((long)b * LC + i0) * LQ;
#pragma unroll
  for (int r = 0; r < 8; r++) {
    int row = w * 8 + r;
    float v[4];
#pragma unroll
    for (int c = 0; c < 4; c++) {
      float sv = Sb[(long)row * LQ + l + 64 * c];
      v[c] = (qms[l + 64 * c] != 0.f) ? NEGV : sv;
    }
    float mx = fmaxf(fmaxf(v[0], v[1]), fmaxf(v[2], v[3]));
#pragma unroll
    for (int o = 1; o < 64; o <<= 1) mx = fmaxf(mx, __shfl_xor(mx, o));
    float e[4]; float sm = 0.f;
#pragma unroll
    for (int c = 0; c < 4; c++) { e[c] = __expf(v[c] - mx); sm += e[c]; }
#pragma unroll
    for (int o = 1; o < 64; o <<= 1) sm += __shfl_xor(sm, o);
    float inv = 1.0f / sm;
#pragma unroll
    for (int c = 0; c < 4; c++) Pr[row * 264 + l + 64 * c] = f2bf(e[c] * inv);
  }
  __syncthreads();
  int lane_m = l & 15, kb = l >> 4;
  int hw2 = (w >> 1) * 64, iw = (w & 1) * 32;
  const unsigned short* Qu = (const unsigned short*)Qp;
  const unsigned short* Tt = (const unsigned short*)(ws + NOFF_T);
  long qrow = (long)b * HH * LQ;
  f32x4 z4 = {0.f, 0.f, 0.f, 0.f};
  f32x4 acc1[4][2], acc2[4][2];
#pragma unroll
  for (int mf = 0; mf < 4; mf++) {
    acc1[mf][0] = z4; acc1[mf][1] = z4;
    acc2[mf][0] = z4; acc2[mf][1] = z4;
  }
#pragma unroll
  for (int kc = 0; kc < 8; kc++) {
    short8v b0 = ldfrag(&Pr[(iw + lane_m) * 264 + kc * 32 + kb * 8]);
    short8v b1 = ldfrag(&Pr[(iw + 16 + lane_m) * 264 + kc * 32 + kb * 8]);
#pragma unroll
    for (int mf = 0; mf < 4; mf++) {
      long ro = qrow + (long)(hw2 + mf * 16 + lane_m) * LQ + kc * 32 + kb * 8;
      short8v a1 = ldfrag(&Qu[ro]);
      acc1[mf][0] = MFMA(a1, b0, acc1[mf][0]);
      acc1[mf][1] = MFMA(a1, b1, acc1[mf][1]);
      short8v a2 = ldfrag(&Tt[ro]);
      acc2[mf][0] = MFMA(a2, b0, acc2[mf][0]);
      acc2[mf][1] = MFMA(a2, b1, acc2[mf][1]);
    }
  }
  unsigned short* o = (unsigned short*)outp;
  const unsigned short* Cu = (const unsigned short*)Cp;
  long ob = (long)b * (4 * HH) * LC;
#pragma unroll
  for (int mf = 0; mf < 4; mf++)
#pragma unroll
    for (int nf = 0; nf < 2; nf++) {
      int i = i0 + iw + nf * 16 + lane_m;
#pragma unroll
      for (int r = 0; r < 4; r++) {
        int h = hw2 + mf * 16 + kb * 4 + r;
        unsigned short craw = Cu[(long)(b * HH + h) * LC + i];
        float cc = bf2f(craw);
        float av = acc1[mf][nf][r], bv = acc2[mf][nf][r];
        long r0 = ob + (long)h * LC + i;
        o[r0] = craw;
        o[r0 + (long)HH * LC] = f2bf(av);
        o[r0 + 2L * HH * LC] = f2bf(cc * av);
        o[r0 + 3L * HH * LC] = f2bf(cc * bv);
      }
    }
}

// =====================================================================
// ==================== legacy fp32 pipeline (MODE 0) ==================
// =====================================================================

template<int MODE>
__global__ __launch_bounds__(256) void k1_S(const void* Cp, const void* Qp, const void* lpp,
                                            float* ws, const int* flag) {
  if (*flag != MODE) return;
  __shared__ float w1s[HH], w2s[HH], w3s[HH];
  __shared__ float Cs[8][32];
  int tid = threadIdx.x;
  int b = blockIdx.y;
  int i0 = blockIdx.x * 32;
  w1s[tid] = ld<MODE>(lpp, tid);
  w2s[tid] = ld<MODE>(lpp, HH + tid);
  w3s[tid] = ld<MODE>(lpp, 2 * HH + tid);
  float acc[32];
#pragma unroll
  for (int ii = 0; ii < 32; ii++) acc[ii] = 0.f;
  float q2acc = 0.f;
  long cbase = (long)b * HH * LC;
  long qbase = (long)b * HH * LQ;
  for (int hc = 0; hc < HH / 8; hc++) {
    __syncthreads();
    {
      int hh = tid >> 5, ii = tid & 31;
      Cs[hh][ii] = ld<MODE>(Cp, cbase + (long)(hc * 8 + hh) * LC + i0 + ii);
    }
    __syncthreads();
#pragma unroll
    for (int hh = 0; hh < 8; hh++) {
      int h = hc * 8 + hh;
      float qv = ld<MODE>(Qp, qbase + (long)h * LQ + tid);
      float coef = w1s[h] + w3s[h] * qv;
      q2acc += w2s[h] * qv;
#pragma unroll
      for (int ii = 0; ii < 32; ii++) acc[ii] += coef * Cs[hh][ii];
    }
  }
  float* Sout = ws + OFF_S + ((long)b * LC + i0) * LQ;
#pragma unroll
  for (int ii = 0; ii < 32; ii++)
    Sout[(long)ii * LQ + tid] = acc[ii] + q2acc;
}

template<int MODE>
__global__ __launch_bounds__(256) void k2a_colpart(const void* cmaskp, const float* ws,
                                                   const int* flag) {
  if (*flag != MODE) return;
  int tid = threadIdx.x;
  int b = blockIdx.y;
  int ch = blockIdx.x;
  const float* Sb = ws + OFF_S + ((long)b * LC + (long)ch * 256) * LQ;
  float m = -INFINITY, l = 0.f;
  for (int ii = 0; ii < 256; ii++) {
    float cm = ld<MODE>(cmaskp, (long)b * LC + ch * 256 + ii);
    float v = (cm != 0.f) ? NEGV : Sb[(long)ii * LQ + tid];
    float nm = fmaxf(m, v);
    l = l * __expf(m - nm) + __expf(v - nm);
    m = nm;
  }
  float* pm = (float*)(ws + OFF_PM);
  float* pl = (float*)(ws + OFF_PL);
  pm[((long)b * 8 + ch) * LQ + tid] = m;
  pl[((long)b * 8 + ch) * LQ + tid] = l;
}

template<int MODE>
__global__ __launch_bounds__(256) void k2b_T(const void* Cp, const void* cmaskp,
                                             float* ws, const int* flag) {
  if (*flag != MODE) return;
  int tid = threadIdx.x;
  int b = blockIdx.y;
  int h0 = blockIdx.x * 32;
  const float* pm = ws + OFF_PM;
  const float* pl = ws + OFF_PL;
  float M = -INFINITY;
#pragma unroll
  for (int c = 0; c < 8; c++) M = fmaxf(M, pm[((long)b * 8 + c) * LQ + tid]);
  float L = 0.f;
#pragma unroll
  for (int c = 0; c < 8; c++)
    L += pl[((long)b * 8 + c) * LQ + tid] * __expf(pm[((long)b * 8 + c) * LQ + tid] - M);
  float Linv = 1.0f / L;

  __shared__ float Cs[32][33];
  __shared__ float cms[32];
  float acc[32];
#pragma unroll
  for (int hh = 0; hh < 32; hh++) acc[hh] = 0.f;
  long cbase = (long)b * HH * LC;
  const float* Sb = ws + OFF_S + (long)b * LC * LQ;
  for (int ic = 0; ic < LC / 32; ic++) {
    int ibase = ic * 32;
    __syncthreads();
#pragma unroll
    for (int it = 0; it < 4; it++) {
      int hh = it * 8 + (tid >> 5);
      int ii = tid & 31;
      Cs[ii][hh] = ld<MODE>(Cp, cbase + (long)(h0 + hh) * LC + ibase + ii);
    }
    if (tid < 32) cms[tid] = ld<MODE>(cmaskp, (long)b * LC + ibase + tid);
    __syncthreads();
#pragma unroll 4
    for (int ii = 0; ii < 32; ii++) {
      float sv = Sb[(long)(ibase + ii) * LQ + tid];
      float p = (cms[ii] != 0.f) ? 0.f : __expf(sv - M) * Linv;
#pragma unroll
      for (int hh = 0; hh < 32; hh++) acc[hh] += p * Cs[ii][hh];
    }
  }
  float* To = ws + OFF_T + ((long)b * HH + h0) * LQ;
#pragma unroll
  for (int hh = 0; hh < 32; hh++)
    To[(long)hh * LQ + tid] = acc[hh];
}

template<int MODE>
__global__ __launch_bounds__(256) void k3_out(const void* Cp, const void* Qp, const void* qmaskp,
                                              const float* ws, void* outp, const int* flag) {
  if (*flag != MODE) return;
  __shared__ __align__(16) float Pst[LQ][36];
  __shared__ float qms[LQ];
  __shared__ float red[32][8];
  __shared__ float rowm[32], rowinv[32];
  int tid = threadIdx.x;
  int b = blockIdx.y;
  int i0 = blockIdx.x * 32;
  qms[tid] = ld<MODE>(qmaskp, (long)b * LQ + tid);
  __syncthreads();

  int r = tid >> 3, s = tid & 7;
  const float* Srow = ws + OFF_S + ((long)b * LC + i0 + r) * LQ;
  float m = -INFINITY;
#pragma unroll 4
  for (int k = 0; k < 32; k++) {
    int j = k * 8 + s;
    float v = (qms[j] != 0.f) ? NEGV : Srow[j];
    m = fmaxf(m, v);
  }
  red[r][s] = m;
  __syncthreads();
  if (s == 0) {
    float mm = red[r][0];
#pragma unroll
    for (int t = 1; t < 8; t++) mm = fmaxf(mm, red[r][t]);
    rowm[r] = mm;
  }
  __syncthreads();
  float rm = rowm[r];
  float l = 0.f;
#pragma unroll 4
  for (int k = 0; k < 32; k++) {
    int j = k * 8 + s;
    float v = (qms[j] != 0.f) ? NEGV : Srow[j];
    float e = __expf(v - rm);
    Pst[j][r] = e;
    l += e;
  }
  red[r][s] = l;
  __syncthreads();
  if (s == 0) {
    float ll = 0.f;
#pragma unroll
    for (int t = 0; t < 8; t++) ll += red[r][t];
    rowinv[r] = 1.0f / ll;
  }
  __syncthreads();
  float ri = rowinv[r];
#pragma unroll 4
  for (int k = 0; k < 32; k++) Pst[k * 8 + s][r] *= ri;
  __syncthreads();

  float accA[32], accB[32];
#pragma unroll
  for (int ii = 0; ii < 32; ii++) { accA[ii] = 0.f; accB[ii] = 0.f; }
  long qbase = ((long)b * HH + tid) * LQ;
  const float* Trow = ws + OFF_T + ((long)b * HH + tid) * LQ;
  for (int j = 0; j < LQ; j++) {
    float qv = ld<MODE>(Qp, qbase + j);
    float tv = Trow[j];
    const float4* pj = (const float4*)&Pst[j][0];
#pragma unroll
    for (int q = 0; q < 8; q++) {
      float4 pv = pj[q];
      accA[q * 4 + 0] += qv * pv.x;  accB[q * 4 + 0] += tv * pv.x;
      accA[q * 4 + 1] += qv * pv.y;  accB[q * 4 + 1] += tv * pv.y;
      accA[q * 4 + 2] += qv * pv.z;  accB[q * 4 + 2] += tv * pv.z;
      accA[q * 4 + 3] += qv * pv.w;  accB[q * 4 + 3] += tv * pv.w;
    }
  }

  long cbase = ((long)b * HH + tid) * LC + i0;
  float cv[32];
#pragma unroll
  for (int ii = 0; ii < 32; ii++) cv[ii] = ld<MODE>(Cp, cbase + ii);

  long ob = (long)b * (4 * HH) * LC;
  {
    float* ofp = (float*)outp;
    float* r0 = ofp + ob + (long)tid * LC + i0;
    float* r1 = ofp + ob + (long)(HH + tid) * LC + i0;
    float* r2 = ofp + ob + (long)(2 * HH + tid) * LC + i0;
    float* r3 = ofp + ob + (long)(3 * HH + tid) * LC + i0;
#pragma unroll
    for (int c = 0; c < 8; c++) {
      int ii = c * 4;
      float4 v0 = make_float4(cv[ii], cv[ii + 1], cv[ii + 2], cv[ii + 3]);
      float4 v1 = make_float4(accA[ii], accA[ii + 1], accA[ii + 2], accA[ii + 3]);
      float4 v2 = make_float4(cv[ii] * accA[ii], cv[ii + 1] * accA[ii + 1],
                              cv[ii + 2] * accA[ii + 2], cv[ii + 3] * accA[ii + 3]);
      float4 v3 = make_float4(cv[ii] * accB[ii], cv[ii + 1] * accB[ii + 1],
                              cv[ii + 2] * accB[ii + 2], cv[ii + 3] * accB[ii + 3]);
      ((float4*)r0)[c] = v0;
      ((float4*)r1)[c] = v1;
      ((float4*)r2)[c] = v2;
      ((float4*)r3)[c] = v3;
    }
  }
}

extern "C" void kernel_launch(void* const* d_in, const int* in_sizes, int n_in,
                              void* d_out, int out_size, void* d_ws, size_t ws_size,
                              hipStream_t stream) {
  const void* C  = d_in[0];
  const void* Q  = d_in[1];
  const void* cm = d_in[2];
  const void* qm = d_in[3];
  const void* lp = d_in[4];
  float* ws = (float*)d_ws;
  int* flag = (int*)(ws + OFF_FLAG);

  sniff_kernel<<<1, 64, 0, stream>>>((const unsigned int*)C, flag);

  // ---- MODE 1: bf16 MFMA pipeline ----
  nk0_bfold<<<dim3(4, BB), 256, 0, stream>>>(Q, lp, ws, flag);
  nk1_S<<<dim3(LC / 64, BB), 256, 0, stream>>>(C, ws, flag);
  nk2a_col<<<dim3(16, BB), 256, 0, stream>>>(cm, ws, flag);
  nk2b_T<<<dim3(4, BB), 512, 0, stream>>>(C, cm, ws, flag);
  nk3_out<<<dim3(LC / 64, BB), 512, 0, stream>>>(C, Q, qm, ws, d_out, flag);

  // ---- MODE 0: legacy fp32 pipeline ----
  dim3 g1(LC / 32, BB), g2a(8, BB), g2b(HH / 32, BB), g3(LC / 32, BB);
  k1_S<0><<<g1, 256, 0, stream>>>(C, Q, lp, ws, flag);
  k2a_colpart<0><<<g2a, 256, 0, stream>>>(cm, ws, flag);
  k2b_T<0><<<g2b, 256, 0, stream>>>(C, cm, ws, flag);
  k3_out<0><<<g3, 256, 0, stream>>>(C, Q, qm, ws, d_out, flag);
}

// Round 2
// 1430.959 us; speedup vs baseline: 2.1561x; 2.1465x over previous
//
#include <hip/hip_runtime.h>

#define BB 64
#define HH 256
#define LC 2048
#define LQ 256
#define NEGV -1e30f

// ---- workspace layout in floats (fits proven 38,010,881-float footprint) ----
// fp32 (MODE 0) pipeline:
//   S fp32 [b][i][j]                  : [0, 33554432)
//   Bfold u16 hi/lo [b][j][2][H]      : [33554432, 37748736)   alive f0->f1
//   T split u16 [b][h][2][LQ]         : [33554432, 37748736)   alive f2b->f3 (aliases Bfold)
//   Q2 fp32 [b][j]                    : [37748736, 37765120)   alive f0->f1
//   PM fp32 [b][8][j]                 : [37748736, 37879808)   alive f2a->f2b (aliases Q2)
//   PL fp32 [b][8][j]                 : [37879808, 38010880)
#define OFF_S    0L
#define FOFF_BF  33554432L
#define FOFF_T   33554432L
#define FOFF_Q2  37748736L
#define FOFF_PM  37748736L
#define FOFF_PL  37879808L
#define OFF_FLAG 38010880L

// bf16 (MODE 1) pipeline offsets (unchanged from prior round)
#define NOFF_BF  33554432L
#define NOFF_Q2  37748736L
#define NOFF_PM  33554432L
#define NOFF_PL  33816576L
#define NOFF_T   34078720L

typedef __attribute__((ext_vector_type(8))) short short8v;   // 8 bf16 (4 VGPRs)
typedef __attribute__((ext_vector_type(4))) float f32x4;

union FragU { uint4 u; short8v h; };

__device__ __forceinline__ short8v ldfrag(const unsigned short* p) {
  FragU f; f.u = *reinterpret_cast<const uint4*>(p); return f.h;
}

#define MFMA(a, b, c) __builtin_amdgcn_mfma_f32_16x16x32_bf16(a, b, c, 0, 0, 0)

template<int MODE>
__device__ __forceinline__ float ld(const void* p, long idx) {
  if (MODE == 1) {
    unsigned short u = ((const unsigned short*)p)[idx];
    return __uint_as_float(((unsigned int)u) << 16);
  } else {
    return ((const float*)p)[idx];
  }
}

__device__ __forceinline__ float bf2f(unsigned short u) {
  return __uint_as_float(((unsigned int)u) << 16);
}

__device__ __forceinline__ unsigned short f2bf(float f) {
  unsigned int u = __float_as_uint(f);
  unsigned int r = (u + 0x7fffu + ((u >> 16) & 1u)) >> 16;
  return (unsigned short)r;
}

// fp32 -> bf16 hi (truncated) + bf16 lo (RNE of exact residual). hi+lo ~ 2^-17 rel.
__device__ __forceinline__ void split1(float v, unsigned short& h, unsigned short& l) {
  unsigned int u = __float_as_uint(v);
  h = (unsigned short)(u >> 16);
  float r = v - __uint_as_float(u & 0xffff0000u);   // exact
  l = f2bf(r);
}

__device__ __forceinline__ void split8(const float4 f0, const float4 f1,
                                       short8v& hi, short8v& lo) {
  float v[8] = {f0.x, f0.y, f0.z, f0.w, f1.x, f1.y, f1.z, f1.w};
#pragma unroll
  for (int e = 0; e < 8; e++) {
    unsigned short h, l;
    split1(v[e], h, l);
    ((unsigned short*)&hi)[e] = h;
    ((unsigned short*)&lo)[e] = l;
  }
}

union U16x8 { uint4 u; unsigned short s[8]; };

// ---------------- dtype sniff ----------------
__global__ void sniff_kernel(const unsigned int* cw, int* flag) {
  __shared__ int cnt[64];
  int tid = threadIdx.x;
  unsigned int w = cw[tid];
  int p = 0;
  for (int h = 0; h < 2; h++) {
    unsigned short u = h ? (unsigned short)(w >> 16) : (unsigned short)(w & 0xffffu);
    float f = __uint_as_float(((unsigned int)u) << 16);
    float a = fabsf(f);
    if ((a >= 1e-5f && a <= 64.0f) || f == 0.0f) p++;
  }
  cnt[tid] = p;
  __syncthreads();
  if (tid == 0) {
    int t = 0;
    for (int i = 0; i < 64; i++) t += cnt[i];
    *flag = (t >= 102) ? 1 : 0;   // 1 = bf16 I/O, 0 = fp32 I/O
  }
}

// =====================================================================
// ============ fp32-input split-bf16 MFMA pipeline (MODE 0) ===========
// =====================================================================

// f0: Bfold[b][j][{hi,lo}][h] = split(w1[h] + w3[h]*Q[h,j]);  Q2[b][j] = sum_h w2[h]Q[h,j]
__global__ __launch_bounds__(256) void f0_bfold(const void* Qp, const void* lpp,
                                                float* ws, const int* flag) {
  if (*flag != 0) return;
  __shared__ __align__(16) float Qs[64][68];
  __shared__ float w1s[HH], w2s[HH], w3s[HH];
  __shared__ float q2red[4][64];
  int t = threadIdx.x, b = blockIdx.y, j0 = blockIdx.x * 64;
  const float* Qf = (const float*)Qp;
  const float* lpf = (const float*)lpp;
  w1s[t] = lpf[t]; w2s[t] = lpf[HH + t]; w3s[t] = lpf[2 * HH + t];
  long qbase = (long)b * HH * LQ;
  unsigned short* Bfw = (unsigned short*)(ws + FOFF_BF);
  int jl = t & 63, hg = t >> 6;
  float q2a = 0.f;
  for (int hp = 0; hp < 4; hp++) {
    int h0 = hp * 64;
    __syncthreads();
    {
      int row = t >> 2, c = t & 3;
      const float4* src = (const float4*)&Qf[qbase + (long)(h0 + row) * LQ + j0 + c * 16];
      float4 v0 = src[0], v1 = src[1], v2 = src[2], v3 = src[3];
      *(float4*)&Qs[row][c * 16]      = v0;
      *(float4*)&Qs[row][c * 16 + 4]  = v1;
      *(float4*)&Qs[row][c * 16 + 8]  = v2;
      *(float4*)&Qs[row][c * 16 + 12] = v3;
    }
    __syncthreads();
    unsigned int hiw[8], low[8];
#pragma unroll
    for (int e = 0; e < 16; e++) {
      int hh = hg * 16 + e;
      int h = h0 + hh;
      float qv = Qs[hh][jl];
      float bb = w1s[h] + w3s[h] * qv;
      q2a += w2s[h] * qv;
      unsigned short bh, bl;
      split1(bb, bh, bl);
      if (e & 1) { hiw[e >> 1] |= ((unsigned int)bh) << 16; low[e >> 1] |= ((unsigned int)bl) << 16; }
      else       { hiw[e >> 1] = bh; low[e >> 1] = bl; }
    }
    long bfb = ((long)b * LQ + j0 + jl) * (2 * HH);
    *(uint4*)&Bfw[bfb + h0 + hg * 16]          = make_uint4(hiw[0], hiw[1], hiw[2], hiw[3]);
    *(uint4*)&Bfw[bfb + h0 + hg * 16 + 8]      = make_uint4(hiw[4], hiw[5], hiw[6], hiw[7]);
    *(uint4*)&Bfw[bfb + HH + h0 + hg * 16]     = make_uint4(low[0], low[1], low[2], low[3]);
    *(uint4*)&Bfw[bfb + HH + h0 + hg * 16 + 8] = make_uint4(low[4], low[5], low[6], low[7]);
  }
  q2red[hg][jl] = q2a;
  __syncthreads();
  if (t < 64)
    ws[FOFF_Q2 + (long)b * LQ + j0 + t] =
        q2red[0][t] + q2red[1][t] + q2red[2][t] + q2red[3][t];
}

// f1: S[i,j] = sum_h C[h,i]*Bfold[j,h] + q2[j]  via 3-term split MFMA, fp32 S out
__global__ __launch_bounds__(256) void f1_S(const void* Cp, float* ws, const int* flag) {
  if (*flag != 0) return;
  __shared__ __align__(16) unsigned short CaH[64 * 40];  // [i][h] pitch 40 u16
  __shared__ __align__(16) unsigned short CaL[64 * 40];
  int t = threadIdx.x, b = blockIdx.y, i0 = blockIdx.x * 64;
  int w = t >> 6, l = t & 63;
  int lane_m = l & 15, kb = l >> 4;
  const float* Cf = (const float*)Cp;
  const unsigned short* Bf = (const unsigned short*)(ws + FOFF_BF);
  long cbase = (long)b * HH * LC;
  f32x4 z4 = {0.f, 0.f, 0.f, 0.f};
  f32x4 acc[4][4];
#pragma unroll
  for (int mf = 0; mf < 4; mf++)
#pragma unroll
    for (int nf = 0; nf < 4; nf++) acc[mf][nf] = z4;

  for (int hc = 0; hc < 8; hc++) {
    int h0 = hc * 32;
    __syncthreads();
#pragma unroll
    for (int hp = 0; hp < 4; hp++) {   // transpose-stage + split C tile [64 i][32 h]
      int hh = hp * 8 + (t >> 5);
      int ii = (t & 31) * 2;
      float2 cw = *(const float2*)&Cf[cbase + (long)(h0 + hh) * LC + i0 + ii];
      unsigned short xh, xl;
      split1(cw.x, xh, xl);
      CaH[ii * 40 + hh] = xh; CaL[ii * 40 + hh] = xl;
      split1(cw.y, xh, xl);
      CaH[(ii + 1) * 40 + hh] = xh; CaL[(ii + 1) * 40 + hh] = xl;
    }
    __syncthreads();
    short8v aH[4], aL[4];
#pragma unroll
    for (int mf = 0; mf < 4; mf++) {
      aH[mf] = ldfrag(&CaH[(mf * 16 + lane_m) * 40 + kb * 8]);
      aL[mf] = ldfrag(&CaL[(mf * 16 + lane_m) * 40 + kb * 8]);
    }
#pragma unroll
    for (int nf = 0; nf < 4; nf++) {
      long jb = ((long)b * LQ + w * 64 + nf * 16 + lane_m) * (2 * HH) + h0 + kb * 8;
      short8v bh = ldfrag(&Bf[jb]);
      short8v bl = ldfrag(&Bf[jb + HH]);
#pragma unroll
      for (int mf = 0; mf < 4; mf++) {
        acc[mf][nf] = MFMA(aH[mf], bh, acc[mf][nf]);
        acc[mf][nf] = MFMA(aH[mf], bl, acc[mf][nf]);
        acc[mf][nf] = MFMA(aL[mf], bh, acc[mf][nf]);
      }
    }
  }
  const float* q2g = ws + FOFF_Q2 + (long)b * LQ;
#pragma unroll
  for (int nf = 0; nf < 4; nf++) {
    int j = w * 64 + nf * 16 + lane_m;
    float q2v = q2g[j];
    float* So = ws + OFF_S + ((long)b * LC + i0 + kb * 4) * LQ + j;
#pragma unroll
    for (int mf = 0; mf < 4; mf++)
#pragma unroll
      for (int r = 0; r < 4; r++)
        So[(long)(mf * 16 + r) * LQ] = acc[mf][nf][r] + q2v;
  }
}

// f2a: column-softmax partials over 8 chunks of 256 i (two-pass)
__global__ __launch_bounds__(256) void f2a_col(const void* cmaskp, float* ws, const int* flag) {
  if (*flag != 0) return;
  __shared__ float cms[256];
  int t = threadIdx.x, ch = blockIdx.x, b = blockIdx.y;
  int ib = ch * 256;
  cms[t] = ((const float*)cmaskp)[(long)b * LC + ib + t];
  __syncthreads();
  const float* Sb = ws + OFF_S + ((long)b * LC + ib) * LQ + t;
  float m = -INFINITY;
#pragma unroll 8
  for (int i = 0; i < 256; i++) {
    float v = (cms[i] != 0.f) ? NEGV : Sb[(long)i * LQ];
    m = fmaxf(m, v);
  }
  float s = 0.f;
#pragma unroll 8
  for (int i = 0; i < 256; i++) {
    float v = (cms[i] != 0.f) ? NEGV : Sb[(long)i * LQ];
    s += __expf(v - m);
  }
  ws[FOFF_PM + ((long)b * 8 + ch) * LQ + t] = m;
  ws[FOFF_PL + ((long)b * 8 + ch) * LQ + t] = s;
}

// f2b: T[h,j] = sum_i Pc[i,j]*C[h,i] via split MFMA; T stored pre-split u16 hi/lo
__global__ __launch_bounds__(512) void f2b_T(const void* Cp, const void* cmaskp,
                                             float* ws, const int* flag) {
  if (*flag != 0) return;
  __shared__ __align__(16) unsigned short PtH[64 * 72];   // [j][i] pitch 72 u16
  __shared__ __align__(16) unsigned short PtL[64 * 72];
  int t = threadIdx.x, b = blockIdx.y, j0 = blockIdx.x * 64;
  int w = t >> 6, l = t & 63;
  int lane_m = l & 15, kb = l >> 4;
  int jj = j0 + l;
  const float* Cf = (const float*)Cp;
  const float* cmf = (const float*)cmaskp;
  float M = -INFINITY;
#pragma unroll
  for (int c = 0; c < 8; c++)
    M = fmaxf(M, ws[FOFF_PM + ((long)b * 8 + c) * LQ + jj]);
  float L = 0.f;
#pragma unroll
  for (int c = 0; c < 8; c++)
    L += ws[FOFF_PL + ((long)b * 8 + c) * LQ + jj] *
         __expf(ws[FOFF_PM + ((long)b * 8 + c) * LQ + jj] - M);
  float Li = 1.0f / L;
  int hw = (w >> 1) * 64, jw = (w & 1) * 32;
  long cbase = (long)b * HH * LC;
  const float* Sb = ws + OFF_S + (long)b * LC * LQ;
  f32x4 z4 = {0.f, 0.f, 0.f, 0.f};
  f32x4 acc[4][2];
#pragma unroll
  for (int mf = 0; mf < 4; mf++) { acc[mf][0] = z4; acc[mf][1] = z4; }

  for (int ic = 0; ic < 32; ic++) {
    int i0 = ic * 64;
    __syncthreads();
    unsigned int pwH[4], pwL[4];
#pragma unroll
    for (int s2 = 0; s2 < 4; s2++) {
      unsigned short h0s, l0s, h1s, l1s;
      {
        int i = i0 + w * 8 + 2 * s2;
        float cm = cmf[(long)b * LC + i];
        float sv = Sb[(long)i * LQ + jj];
        float p = (cm != 0.f) ? 0.f : __expf(sv - M) * Li;
        split1(p, h0s, l0s);
      }
      {
        int i = i0 + w * 8 + 2 * s2 + 1;
        float cm = cmf[(long)b * LC + i];
        float sv = Sb[(long)i * LQ + jj];
        float p = (cm != 0.f) ? 0.f : __expf(sv - M) * Li;
        split1(p, h1s, l1s);
      }
      pwH[s2] = (unsigned int)h0s | ((unsigned int)h1s << 16);
      pwL[s2] = (unsigned int)l0s | ((unsigned int)l1s << 16);
    }
    *(uint4*)&PtH[l * 72 + w * 8] = make_uint4(pwH[0], pwH[1], pwH[2], pwH[3]);
    *(uint4*)&PtL[l * 72 + w * 8] = make_uint4(pwL[0], pwL[1], pwL[2], pwL[3]);
    __syncthreads();
#pragma unroll
    for (int ks = 0; ks < 2; ks++) {
      short8v b0h = ldfrag(&PtH[(jw + lane_m) * 72 + ks * 32 + kb * 8]);
      short8v b0l = ldfrag(&PtL[(jw + lane_m) * 72 + ks * 32 + kb * 8]);
      short8v b1h = ldfrag(&PtH[(jw + 16 + lane_m) * 72 + ks * 32 + kb * 8]);
      short8v b1l = ldfrag(&PtL[(jw + 16 + lane_m) * 72 + ks * 32 + kb * 8]);
#pragma unroll
      for (int mf = 0; mf < 4; mf++) {
        const float* cp = Cf + cbase + (long)(hw + mf * 16 + lane_m) * LC + i0 + ks * 32 + kb * 8;
        short8v aH, aL;
        split8(((const float4*)cp)[0], ((const float4*)cp)[1], aH, aL);
        acc[mf][0] = MFMA(aH, b0h, acc[mf][0]);
        acc[mf][0] = MFMA(aH, b0l, acc[mf][0]);
        acc[mf][0] = MFMA(aL, b0h, acc[mf][0]);
        acc[mf][1] = MFMA(aH, b1h, acc[mf][1]);
        acc[mf][1] = MFMA(aH, b1l, acc[mf][1]);
        acc[mf][1] = MFMA(aL, b1h, acc[mf][1]);
      }
    }
  }
  unsigned short* Tu = (unsigned short*)(ws + FOFF_T);
#pragma unroll
  for (int mf = 0; mf < 4; mf++)
#pragma unroll
    for (int nf = 0; nf < 2; nf++)
#pragma unroll
      for (int r = 0; r < 4; r++) {
        int h = hw + mf * 16 + kb * 4 + r;
        int j = j0 + jw + nf * 16 + lane_m;
        unsigned short th, tl;
        split1(acc[mf][nf][r], th, tl);
        long tb = ((long)b * HH + h) * (2 * LQ);
        Tu[tb + j] = th;
        Tu[tb + LQ + j] = tl;
      }
}

// f3: row softmax -> Pr split in LDS -> A=Pr@Qt^T, Bt=Pr@Tt^T via split MFMA -> fused out
__global__ __launch_bounds__(512) void f3_out(const void* Cp, const void* Qp, const void* qmaskp,
                                              float* ws, void* outp, const int* flag) {
  if (*flag != 0) return;
  __shared__ __align__(16) unsigned short PrH[32 * 264];  // [i][j] pitch 264 u16
  __shared__ __align__(16) unsigned short PrL[32 * 264];
  __shared__ float qms[LQ];
  int t = threadIdx.x, b = blockIdx.y, i0 = blockIdx.x * 32;
  int w = t >> 6, l = t & 63;
  const float* Cf = (const float*)Cp;
  const float* Qf = (const float*)Qp;
  if (t < LQ) qms[t] = ((const float*)qmaskp)[(long)b * LQ + t];
  __syncthreads();
  const float* Sb = ws + OFF_S + ((long)b * LC + i0) * LQ;
#pragma unroll
  for (int r = 0; r < 4; r++) {
    int row = w * 4 + r;
    float v[4];
#pragma unroll
    for (int c = 0; c < 4; c++) {
      float sv = Sb[(long)row * LQ + l + 64 * c];
      v[c] = (qms[l + 64 * c] != 0.f) ? NEGV : sv;
    }
    float mx = fmaxf(fmaxf(v[0], v[1]), fmaxf(v[2], v[3]));
#pragma unroll
    for (int o2 = 1; o2 < 64; o2 <<= 1) mx = fmaxf(mx, __shfl_xor(mx, o2));
    float e[4]; float sm = 0.f;
#pragma unroll
    for (int c = 0; c < 4; c++) { e[c] = __expf(v[c] - mx); sm += e[c]; }
#pragma unroll
    for (int o2 = 1; o2 < 64; o2 <<= 1) sm += __shfl_xor(sm, o2);
    float inv = 1.0f / sm;
#pragma unroll
    for (int c = 0; c < 4; c++) {
      unsigned short ph, pl;
      split1(e[c] * inv, ph, pl);
      PrH[row * 264 + l + 64 * c] = ph;
      PrL[row * 264 + l + 64 * c] = pl;
    }
  }
  __syncthreads();
  int lane_m = l & 15, kb = l >> 4;
  int hw2 = w * 32;
  const unsigned short* Tu = (const unsigned short*)(ws + FOFF_T);
  long qrow = (long)b * HH * LQ;
  f32x4 z4 = {0.f, 0.f, 0.f, 0.f};
  f32x4 acc1[2][2], acc2[2][2];
#pragma unroll
  for (int mf = 0; mf < 2; mf++) {
    acc1[mf][0] = z4; acc1[mf][1] = z4;
    acc2[mf][0] = z4; acc2[mf][1] = z4;
  }
#pragma unroll
  for (int kc = 0; kc < 8; kc++) {
    short8v b0h = ldfrag(&PrH[lane_m * 264 + kc * 32 + kb * 8]);
    short8v b0l = ldfrag(&PrL[lane_m * 264 + kc * 32 + kb * 8]);
    short8v b1h = ldfrag(&PrH[(16 + lane_m) * 264 + kc * 32 + kb * 8]);
    short8v b1l = ldfrag(&PrL[(16 + lane_m) * 264 + kc * 32 + kb * 8]);
#pragma unroll
    for (int mf = 0; mf < 2; mf++) {
      int h = hw2 + mf * 16 + lane_m;
      const float* qp = Qf + qrow + (long)h * LQ + kc * 32 + kb * 8;
      short8v a1H, a1L;
      split8(((const float4*)qp)[0], ((const float4*)qp)[1], a1H, a1L);
      long tb = ((long)b * HH + h) * (2 * LQ) + kc * 32 + kb * 8;
      short8v a2H = ldfrag(&Tu[tb]);
      short8v a2L = ldfrag(&Tu[tb + LQ]);
      acc1[mf][0] = MFMA(a1H, b0h, acc1[mf][0]);
      acc1[mf][0] = MFMA(a1H, b0l, acc1[mf][0]);
      acc1[mf][0] = MFMA(a1L, b0h, acc1[mf][0]);
      acc1[mf][1] = MFMA(a1H, b1h, acc1[mf][1]);
      acc1[mf][1] = MFMA(a1H, b1l, acc1[mf][1]);
      acc1[mf][1] = MFMA(a1L, b1h, acc1[mf][1]);
      acc2[mf][0] = MFMA(a2H, b0h, acc2[mf][0]);
      acc2[mf][0] = MFMA(a2H, b0l, acc2[mf][0]);
      acc2[mf][0] = MFMA(a2L, b0h, acc2[mf][0]);
      acc2[mf][1] = MFMA(a2H, b1h, acc2[mf][1]);
      acc2[mf][1] = MFMA(a2H, b1l, acc2[mf][1]);
      acc2[mf][1] = MFMA(a2L, b1h, acc2[mf][1]);
    }
  }
  float* o = (float*)outp;
  long ob = (long)b * (4 * HH) * LC;
#pragma unroll
  for (int mf = 0; mf < 2; mf++)
#pragma unroll
    for (int nf = 0; nf < 2; nf++) {
      int i = i0 + nf * 16 + lane_m;
#pragma unroll
      for (int r = 0; r < 4; r++) {
        int h = hw2 + mf * 16 + kb * 4 + r;
        float cc = Cf[((long)b * HH + h) * LC + i];
        float av = acc1[mf][nf][r], bv = acc2[mf][nf][r];
        long r0 = ob + (long)h * LC + i;
        o[r0] = cc;
        o[r0 + (long)HH * LC] = av;
        o[r0 + 2L * HH * LC] = cc * av;
        o[r0 + 3L * HH * LC] = cc * bv;
      }
    }
}

// =====================================================================
// ==================== bf16 MFMA pipeline (MODE 1) ====================
// =====================================================================

__global__ __launch_bounds__(256) void nk0_bfold(const void* Qp, const void* lpp,
                                                 float* ws, const int* flag) {
  if (*flag != 1) return;
  __shared__ __align__(16) unsigned short Qs[64 * 72];
  __shared__ float w1s[HH], w2s[HH], w3s[HH];
  __shared__ float q2red[4][64];
  int t = threadIdx.x;
  int b = blockIdx.y, j0 = blockIdx.x * 64;
  w1s[t] = ld<1>(lpp, t);
  w2s[t] = ld<1>(lpp, HH + t);
  w3s[t] = ld<1>(lpp, 2 * HH + t);
  const unsigned short* Qu = (const unsigned short*)Qp;
  long qbase = (long)b * HH * LQ;
  unsigned short* Bf = (unsigned short*)(ws + NOFF_BF);
  int jl = t & 63, hg = t >> 6;
  float q2a = 0.f;
  for (int hp = 0; hp < 4; hp++) {
    int h0 = hp * 64;
    __syncthreads();
    {
      int row = t >> 2, c = t & 3;
      const uint4* src = (const uint4*)&Qu[qbase + (long)(h0 + row) * LQ + j0 + c * 16];
      uint4 v0 = src[0]; uint4 v1 = src[1];
      *(uint4*)&Qs[row * 72 + c * 16] = v0;
      *(uint4*)&Qs[row * 72 + c * 16 + 8] = v1;
    }
    __syncthreads();
    unsigned int hiw[8], low[8];
#pragma unroll
    for (int e = 0; e < 16; e++) {
      int hh = hg * 16 + e;
      int h = h0 + hh;
      float qv = bf2f(Qs[hh * 72 + jl]);
      float bb = w1s[h] + w3s[h] * qv;
      q2a += w2s[h] * qv;
      unsigned short bh = f2bf(bb);
      float res = bb - bf2f(bh);
      unsigned short bl = f2bf(res);
      if (e & 1) { hiw[e >> 1] |= ((unsigned int)bh) << 16; low[e >> 1] |= ((unsigned int)bl) << 16; }
      else       { hiw[e >> 1] = bh; low[e >> 1] = bl; }
    }
    long bfb = ((long)b * LQ + j0 + jl) * (2 * HH);
    *(uint4*)&Bf[bfb + h0 + hg * 16]      = make_uint4(hiw[0], hiw[1], hiw[2], hiw[3]);
    *(uint4*)&Bf[bfb + h0 + hg * 16 + 8]  = make_uint4(hiw[4], hiw[5], hiw[6], hiw[7]);
    *(uint4*)&Bf[bfb + HH + h0 + hg * 16]     = make_uint4(low[0], low[1], low[2], low[3]);
    *(uint4*)&Bf[bfb + HH + h0 + hg * 16 + 8] = make_uint4(low[4], low[5], low[6], low[7]);
  }
  q2red[hg][jl] = q2a;
  __syncthreads();
  if (t < 64)
    ws[NOFF_Q2 + (long)b * LQ + j0 + t] =
        q2red[0][t] + q2red[1][t] + q2red[2][t] + q2red[3][t];
}

__global__ __launch_bounds__(256) void nk1_S(const void* Cp, float* ws, const int* flag) {
  if (*flag != 1) return;
  __shared__ __align__(16) unsigned short Ca[64 * 40];
  int t = threadIdx.x;
  int b = blockIdx.y, i0 = blockIdx.x * 64;
  int w = t >> 6, l = t & 63;
  int lane_m = l & 15, kb = l >> 4;
  const unsigned short* Cu = (const unsigned short*)Cp;
  const unsigned short* Bf = (const unsigned short*)(ws + NOFF_BF);
  long cbase = (long)b * HH * LC;
  f32x4 z4 = {0.f, 0.f, 0.f, 0.f};
  f32x4 acc[4][4];
#pragma unroll
  for (int mf = 0; mf < 4; mf++)
#pragma unroll
    for (int nf = 0; nf < 4; nf++) acc[mf][nf] = z4;

  for (int hc = 0; hc < 8; hc++) {
    int h0 = hc * 32;
    __syncthreads();
#pragma unroll
    for (int hp = 0; hp < 4; hp++) {
      int hh = hp * 8 + (t >> 5);
      int ii = (t & 31) * 2;
      unsigned int cw = *(const unsigned int*)&Cu[cbase + (long)(h0 + hh) * LC + i0 + ii];
      Ca[ii * 40 + hh] = (unsigned short)(cw & 0xffffu);
      Ca[(ii + 1) * 40 + hh] = (unsigned short)(cw >> 16);
    }
    __syncthreads();
    short8v afr[4];
#pragma unroll
    for (int mf = 0; mf < 4; mf++)
      afr[mf] = ldfrag(&Ca[(mf * 16 + lane_m) * 40 + kb * 8]);
#pragma unroll
    for (int nf = 0; nf < 4; nf++) {
      long jb = ((long)b * LQ + w * 64 + nf * 16 + lane_m) * (2 * HH) + h0 + kb * 8;
      short8v bh = ldfrag(&Bf[jb]);
      short8v bl = ldfrag(&Bf[jb + HH]);
#pragma unroll
      for (int mf = 0; mf < 4; mf++) {
        acc[mf][nf] = MFMA(afr[mf], bh, acc[mf][nf]);
        acc[mf][nf] = MFMA(afr[mf], bl, acc[mf][nf]);
      }
    }
  }
  const float* q2g = ws + NOFF_Q2 + (long)b * LQ;
#pragma unroll
  for (int nf = 0; nf < 4; nf++) {
    int j = w * 64 + nf * 16 + lane_m;
    float q2v = q2g[j];
    float* So = ws + OFF_S + ((long)b * LC + i0 + kb * 4) * LQ + j;
#pragma unroll
    for (int mf = 0; mf < 4; mf++)
#pragma unroll
      for (int r = 0; r < 4; r++)
        So[(long)(mf * 16 + r) * LQ] = acc[mf][nf][r] + q2v;
  }
}

__global__ __launch_bounds__(256) void nk2a_col(const void* cmaskp, float* ws, const int* flag) {
  if (*flag != 1) return;
  __shared__ float cms[128];
  int t = threadIdx.x, ch = blockIdx.x, b = blockIdx.y;
  int ib = ch * 128;
  if (t < 128) cms[t] = ld<1>(cmaskp, (long)b * LC + ib + t);
  __syncthreads();
  const float* Sb = ws + OFF_S + ((long)b * LC + ib) * LQ + t;
  float m = -INFINITY;
#pragma unroll 8
  for (int i = 0; i < 128; i++) {
    float v = (cms[i] != 0.f) ? NEGV : Sb[(long)i * LQ];
    m = fmaxf(m, v);
  }
  float s = 0.f;
#pragma unroll 8
  for (int i = 0; i < 128; i++) {
    float v = (cms[i] != 0.f) ? NEGV : Sb[(long)i * LQ];
    s += __expf(v - m);
  }
  ws[NOFF_PM + ((long)b * 16 + ch) * LQ + t] = m;
  ws[NOFF_PL + ((long)b * 16 + ch) * LQ + t] = s;
}

__global__ __launch_bounds__(512) void nk2b_T(const void* Cp, const void* cmaskp,
                                              float* ws, const int* flag) {
  if (*flag != 1) return;
  __shared__ __align__(16) unsigned short Pt[64 * 72];
  int t = threadIdx.x, b = blockIdx.y, j0 = blockIdx.x * 64;
  int w = t >> 6, l = t & 63;
  int lane_m = l & 15, kb = l >> 4;
  int jj = j0 + l;
  float M = -INFINITY;
#pragma unroll
  for (int c = 0; c < 16; c++)
    M = fmaxf(M, ws[NOFF_PM + ((long)b * 16 + c) * LQ + jj]);
  float L = 0.f;
#pragma unroll
  for (int c = 0; c < 16; c++)
    L += ws[NOFF_PL + ((long)b * 16 + c) * LQ + jj] *
         __expf(ws[NOFF_PM + ((long)b * 16 + c) * LQ + jj] - M);
  float Li = 1.0f / L;
  int hw = (w >> 1) * 64, jw = (w & 1) * 32;
  const unsigned short* Cu = (const unsigned short*)Cp;
  long cbase = (long)b * HH * LC;
  const float* Sb = ws + OFF_S + (long)b * LC * LQ;
  f32x4 z4 = {0.f, 0.f, 0.f, 0.f};
  f32x4 acc[4][2];
#pragma unroll
  for (int mf = 0; mf < 4; mf++) { acc[mf][0] = z4; acc[mf][1] = z4; }

  for (int ic = 0; ic < 32; ic++) {
    int i0 = ic * 64;
    __syncthreads();
    unsigned int pw[4];
#pragma unroll
    for (int s2 = 0; s2 < 4; s2++) {
      unsigned int lo16, hi16;
      {
        int i = i0 + w * 8 + 2 * s2;
        float cm = ld<1>(cmaskp, (long)b * LC + i);
        float sv = Sb[(long)i * LQ + jj];
        float p = (cm != 0.f) ? 0.f : __expf(sv - M) * Li;
        lo16 = f2bf(p);
      }
      {
        int i = i0 + w * 8 + 2 * s2 + 1;
        float cm = ld<1>(cmaskp, (long)b * LC + i);
        float sv = Sb[(long)i * LQ + jj];
        float p = (cm != 0.f) ? 0.f : __expf(sv - M) * Li;
        hi16 = f2bf(p);
      }
      pw[s2] = lo16 | (hi16 << 16);
    }
    *(uint4*)&Pt[l * 72 + w * 8] = make_uint4(pw[0], pw[1], pw[2], pw[3]);
    __syncthreads();
#pragma unroll
    for (int ks = 0; ks < 2; ks++) {
      short8v b0 = ldfrag(&Pt[(jw + lane_m) * 72 + ks * 32 + kb * 8]);
      short8v b1 = ldfrag(&Pt[(jw + 16 + lane_m) * 72 + ks * 32 + kb * 8]);
#pragma unroll
      for (int mf = 0; mf < 4; mf++) {
        short8v a = ldfrag(&Cu[cbase + (long)(hw + mf * 16 + lane_m) * LC + i0 + ks * 32 + kb * 8]);
        acc[mf][0] = MFMA(a, b0, acc[mf][0]);
        acc[mf][1] = MFMA(a, b1, acc[mf][1]);
      }
    }
  }
  unsigned short* Tt = (unsigned short*)(ws + NOFF_T);
#pragma unroll
  for (int mf = 0; mf < 4; mf++)
#pragma unroll
    for (int nf = 0; nf < 2; nf++)
#pragma unroll
      for (int r = 0; r < 4; r++) {
        int h = hw + mf * 16 + kb * 4 + r;
        int j = j0 + jw + nf * 16 + lane_m;
        Tt[((long)b * HH + h) * LQ + j] = f2bf(acc[mf][nf][r]);
      }
}

__global__ __launch_bounds__(512) void nk3_out(const void* Cp, const void* Qp, const void* qmaskp,
                                               float* ws, void* outp, const int* flag) {
  if (*flag != 1) return;
  __shared__ __align__(16) unsigned short Pr[64 * 264];
  __shared__ float qms[LQ];
  int t = threadIdx.x, b = blockIdx.y, i0 = blockIdx.x * 64;
  int w = t >> 6, l = t & 63;
  if (t < LQ) qms[t] = ld<1>(qmaskp, (long)b * LQ + t);
  __syncthreads();
  const float* Sb = ws + OFF_S + ((long)b * LC + i0) * LQ;
#pragma unroll
  for (int r = 0; r < 8; r++) {
    int row = w * 8 + r;
    float v[4];
#pragma unroll
    for (int c = 0; c < 4; c++) {
      float sv = Sb[(long)row * LQ + l + 64 * c];
      v[c] = (qms[l + 64 * c] != 0.f) ? NEGV : sv;
    }
    float mx = fmaxf(fmaxf(v[0], v[1]), fmaxf(v[2], v[3]));
#pragma unroll
    for (int o = 1; o < 64; o <<= 1) mx = fmaxf(mx, __shfl_xor(mx, o));
    float e[4]; float sm = 0.f;
#pragma unroll
    for (int c = 0; c < 4; c++) { e[c] = __expf(v[c] - mx); sm += e[c]; }
#pragma unroll
    for (int o = 1; o < 64; o <<= 1) sm += __shfl_xor(sm, o);
    float inv = 1.0f / sm;
#pragma unroll
    for (int c = 0; c < 4; c++) Pr[row * 264 + l + 64 * c] = f2bf(e[c] * inv);
  }
  __syncthreads();
  int lane_m = l & 15, kb = l >> 4;
  int hw2 = (w >> 1) * 64, iw = (w & 1) * 32;
  const unsigned short* Qu = (const unsigned short*)Qp;
  const unsigned short* Tt = (const unsigned short*)(ws + NOFF_T);
  long qrow = (long)b * HH * LQ;
  f32x4 z4 = {0.f, 0.f, 0.f, 0.f};
  f32x4 acc1[4][2], acc2[4][2];
#pragma unroll
  for (int mf = 0; mf < 4; mf++) {
    acc1[mf][0] = z4; acc1[mf][1] = z4;
    acc2[mf][0] = z4; acc2[mf][1] = z4;
  }
#pragma unroll
  for (int kc = 0; kc < 8; kc++) {
    short8v b0 = ldfrag(&Pr[(iw + lane_m) * 264 + kc * 32 + kb * 8]);
    short8v b1 = ldfrag(&Pr[(iw + 16 + lane_m) * 264 + kc * 32 + kb * 8]);
#pragma unroll
    for (int mf = 0; mf < 4; mf++) {
      long ro = qrow + (long)(hw2 + mf * 16 + lane_m) * LQ + kc * 32 + kb * 8;
      short8v a1 = ldfrag(&Qu[ro]);
      acc1[mf][0] = MFMA(a1, b0, acc1[mf][0]);
      acc1[mf][1] = MFMA(a1, b1, acc1[mf][1]);
      short8v a2 = ldfrag(&Tt[ro]);
      acc2[mf][0] = MFMA(a2, b0, acc2[mf][0]);
      acc2[mf][1] = MFMA(a2, b1, acc2[mf][1]);
    }
  }
  unsigned short* o = (unsigned short*)outp;
  const unsigned short* Cu = (const unsigned short*)Cp;
  long ob = (long)b * (4 * HH) * LC;
#pragma unroll
  for (int mf = 0; mf < 4; mf++)
#pragma unroll
    for (int nf = 0; nf < 2; nf++) {
      int i = i0 + iw + nf * 16 + lane_m;
#pragma unroll
      for (int r = 0; r < 4; r++) {
        int h = hw2 + mf * 16 + kb * 4 + r;
        unsigned short craw = Cu[(long)(b * HH + h) * LC + i];
        float cc = bf2f(craw);
        float av = acc1[mf][nf][r], bv = acc2[mf][nf][r];
        long r0 = ob + (long)h * LC + i;
        o[r0] = craw;
        o[r0 + (long)HH * LC] = f2bf(av);
        o[r0 + 2L * HH * LC] = f2bf(cc * av);
        o[r0 + 3L * HH * LC] = f2bf(cc * bv);
      }
    }
}

extern "C" void kernel_launch(void* const* d_in, const int* in_sizes, int n_in,
                              void* d_out, int out_size, void* d_ws, size_t ws_size,
                              hipStream_t stream) {
  const void* C  = d_in[0];
  const void* Q  = d_in[1];
  const void* cm = d_in[2];
  const void* qm = d_in[3];
  const void* lp = d_in[4];
  float* ws = (float*)d_ws;
  int* flag = (int*)(ws + OFF_FLAG);

  sniff_kernel<<<1, 64, 0, stream>>>((const unsigned int*)C, flag);

  // ---- MODE 0: fp32-input split-bf16 MFMA pipeline ----
  f0_bfold<<<dim3(4, BB), 256, 0, stream>>>(Q, lp, ws, flag);
  f1_S<<<dim3(LC / 64, BB), 256, 0, stream>>>(C, ws, flag);
  f2a_col<<<dim3(8, BB), 256, 0, stream>>>(cm, ws, flag);
  f2b_T<<<dim3(4, BB), 512, 0, stream>>>(C, cm, ws, flag);
  f3_out<<<dim3(LC / 32, BB), 512, 0, stream>>>(C, Q, qm, ws, d_out, flag);

  // ---- MODE 1: bf16 MFMA pipeline ----
  nk0_bfold<<<dim3(4, BB), 256, 0, stream>>>(Q, lp, ws, flag);
  nk1_S<<<dim3(LC / 64, BB), 256, 0, stream>>>(C, ws, flag);
  nk2a_col<<<dim3(16, BB), 256, 0, stream>>>(cm, ws, flag);
  nk2b_T<<<dim3(4, BB), 512, 0, stream>>>(C, cm, ws, flag);
  nk3_out<<<dim3(LC / 64, BB), 512, 0, stream>>>(C, Q, qm, ws, d_out, flag);
}

// Round 3
// 1273.862 us; speedup vs baseline: 2.4220x; 1.1233x over previous
//
#include <hip/hip_runtime.h>

#define BB 64
#define HH 256
#define LC 2048
#define LQ 256
#define NEGV -1e30f

// ---- MODE0 (fp32 I/O) workspace layout in floats ----
//   X   u16 [b][i][j]        : [0, 16777216)             exp(S - mr[i]), bf16
//   BF  u16 [b][j][2H]       : [16777216, 20971520)      Bfold hi/lo (f0 -> g1)
//   QS  u16 [b][h][2LQ]      : [20971520, 25165824)      qm0*Q split hi/lo (g0b -> g3)
//   TS  u16 [b][h][2LQ]      : [25165824, 29360128)      qm0*T split hi/lo (g2 -> g3)
//   MR  f32 [b][LC]          : [29360128, 29491200)
//   LR  f32 [b][LC] (1/lr)   : [29491200, 29622272)
//   Q2  f32 [b][LQ]          : [29622272, 29638656)
//   K   u32 [b]              : [29638656, 29638720)      encoded per-batch max mr
#define GOFF_X    0L
#define GOFF_BF   16777216L
#define GOFF_QS   20971520L
#define GOFF_TS   25165824L
#define GOFF_MR   29360128L
#define GOFF_LR   29491200L
#define GOFF_Q2   29622272L
#define GOFF_K    29638656L
#define OFF_FLAG  38010880L

// MODE1 (bf16 I/O) pipeline offsets (unchanged)
#define OFF_S    0L
#define NOFF_BF  33554432L
#define NOFF_Q2  37748736L
#define NOFF_PM  33554432L
#define NOFF_PL  33816576L
#define NOFF_T   34078720L

typedef __attribute__((ext_vector_type(8))) short short8v;   // 8 bf16 (4 VGPRs)
typedef __attribute__((ext_vector_type(4))) float f32x4;

union FragU { uint4 u; short8v h; };

__device__ __forceinline__ short8v ldfrag(const unsigned short* p) {
  FragU f; f.u = *reinterpret_cast<const uint4*>(p); return f.h;
}

#define MFMA(a, b, c) __builtin_amdgcn_mfma_f32_16x16x32_bf16(a, b, c, 0, 0, 0)

template<int MODE>
__device__ __forceinline__ float ld(const void* p, long idx) {
  if (MODE == 1) {
    unsigned short u = ((const unsigned short*)p)[idx];
    return __uint_as_float(((unsigned int)u) << 16);
  } else {
    return ((const float*)p)[idx];
  }
}

__device__ __forceinline__ float bf2f(unsigned short u) {
  return __uint_as_float(((unsigned int)u) << 16);
}

__device__ __forceinline__ unsigned short f2bf(float f) {
  unsigned int u = __float_as_uint(f);
  unsigned int r = (u + 0x7fffu + ((u >> 16) & 1u)) >> 16;
  return (unsigned short)r;
}

// fp32 -> bf16 hi (truncated) + bf16 lo (RNE of exact residual)
__device__ __forceinline__ void split1(float v, unsigned short& h, unsigned short& l) {
  unsigned int u = __float_as_uint(v);
  h = (unsigned short)(u >> 16);
  float r = v - __uint_as_float(u & 0xffff0000u);   // exact
  l = f2bf(r);
}

__device__ __forceinline__ void split8(const float4 f0, const float4 f1,
                                       short8v& hi, short8v& lo) {
  float v[8] = {f0.x, f0.y, f0.z, f0.w, f1.x, f1.y, f1.z, f1.w};
#pragma unroll
  for (int e = 0; e < 8; e++) {
    unsigned short h, l;
    split1(v[e], h, l);
    ((unsigned short*)&hi)[e] = h;
    ((unsigned short*)&lo)[e] = l;
  }
}

union U16x8 { uint4 u; unsigned short s[8]; };

// order-preserving float<->uint encode for atomicMax
__device__ __forceinline__ unsigned int fenc(float f) {
  unsigned int u = __float_as_uint(f);
  return (u >> 31) ? ~u : (u | 0x80000000u);
}
__device__ __forceinline__ float fdec(unsigned int e) {
  return (e >> 31) ? __uint_as_float(e ^ 0x80000000u) : __uint_as_float(~e);
}

// ---------------- dtype sniff + per-batch K init ----------------
__global__ void sniff_kernel(const unsigned int* cw, int* flag, unsigned int* kz) {
  __shared__ int cnt[64];
  int tid = threadIdx.x;
  unsigned int w = cw[tid];
  int p = 0;
  for (int h = 0; h < 2; h++) {
    unsigned short u = h ? (unsigned short)(w >> 16) : (unsigned short)(w & 0xffffu);
    float f = __uint_as_float(((unsigned int)u) << 16);
    float a = fabsf(f);
    if ((a >= 1e-5f && a <= 64.0f) || f == 0.0f) p++;
  }
  cnt[tid] = p;
  kz[tid] = 0u;     // encoded -inf
  __syncthreads();
  if (tid == 0) {
    int t = 0;
    for (int i = 0; i < 64; i++) t += cnt[i];
    *flag = (t >= 102) ? 1 : 0;   // 1 = bf16 I/O, 0 = fp32 I/O
  }
}

// =====================================================================
// ============ fp32-input split-bf16 MFMA pipeline (MODE 0) ===========
// =====================================================================

// f0: Bfold[b][j][{hi,lo}][h] = split(w1[h] + w3[h]*Q[h,j]);  Q2[b][j] = sum_h w2[h]Q[h,j]
__global__ __launch_bounds__(256) void f0_bfold(const void* Qp, const void* lpp,
                                                float* ws, const int* flag) {
  if (*flag != 0) return;
  __shared__ __align__(16) float Qs[64][68];
  __shared__ float w1s[HH], w2s[HH], w3s[HH];
  __shared__ float q2red[4][64];
  int t = threadIdx.x, b = blockIdx.y, j0 = blockIdx.x * 64;
  const float* Qf = (const float*)Qp;
  const float* lpf = (const float*)lpp;
  w1s[t] = lpf[t]; w2s[t] = lpf[HH + t]; w3s[t] = lpf[2 * HH + t];
  long qbase = (long)b * HH * LQ;
  unsigned short* Bfw = (unsigned short*)(ws + GOFF_BF);
  int jl = t & 63, hg = t >> 6;
  float q2a = 0.f;
  for (int hp = 0; hp < 4; hp++) {
    int h0 = hp * 64;
    __syncthreads();
    {
      int row = t >> 2, c = t & 3;
      const float4* src = (const float4*)&Qf[qbase + (long)(h0 + row) * LQ + j0 + c * 16];
      float4 v0 = src[0], v1 = src[1], v2 = src[2], v3 = src[3];
      *(float4*)&Qs[row][c * 16]      = v0;
      *(float4*)&Qs[row][c * 16 + 4]  = v1;
      *(float4*)&Qs[row][c * 16 + 8]  = v2;
      *(float4*)&Qs[row][c * 16 + 12] = v3;
    }
    __syncthreads();
    unsigned int hiw[8], low[8];
#pragma unroll
    for (int e = 0; e < 16; e++) {
      int hh = hg * 16 + e;
      int h = h0 + hh;
      float qv = Qs[hh][jl];
      float bb = w1s[h] + w3s[h] * qv;
      q2a += w2s[h] * qv;
      unsigned short bh, bl;
      split1(bb, bh, bl);
      if (e & 1) { hiw[e >> 1] |= ((unsigned int)bh) << 16; low[e >> 1] |= ((unsigned int)bl) << 16; }
      else       { hiw[e >> 1] = bh; low[e >> 1] = bl; }
    }
    long bfb = ((long)b * LQ + j0 + jl) * (2 * HH);
    *(uint4*)&Bfw[bfb + h0 + hg * 16]          = make_uint4(hiw[0], hiw[1], hiw[2], hiw[3]);
    *(uint4*)&Bfw[bfb + h0 + hg * 16 + 8]      = make_uint4(hiw[4], hiw[5], hiw[6], hiw[7]);
    *(uint4*)&Bfw[bfb + HH + h0 + hg * 16]     = make_uint4(low[0], low[1], low[2], low[3]);
    *(uint4*)&Bfw[bfb + HH + h0 + hg * 16 + 8] = make_uint4(low[4], low[5], low[6], low[7]);
  }
  q2red[hg][jl] = q2a;
  __syncthreads();
  if (t < 64)
    ws[GOFF_Q2 + (long)b * LQ + j0 + t] =
        q2red[0][t] + q2red[1][t] + q2red[2][t] + q2red[3][t];
}

// g0b: QS[b][h][{hi,lo}][j] = split(Q[h,j] * qm0[j])
__global__ __launch_bounds__(256) void g0b_Qsplit(const void* Qp, const void* qmaskp,
                                                  float* ws, const int* flag) {
  if (*flag != 0) return;
  __shared__ float qms[LQ];
  int t = threadIdx.x, b = blockIdx.y, hb = blockIdx.x;
  qms[t] = (((const float*)qmaskp)[(long)b * LQ + t] != 0.f) ? 0.f : 1.f;
  __syncthreads();
  const float* Qf = (const float*)Qp;
  unsigned short* Qs = (unsigned short*)(ws + GOFF_QS);
#pragma unroll
  for (int it = 0; it < 4; it++) {
    int o = t + 256 * it;          // octet id 0..1023 over 32h x 32octets
    int hh = o >> 5;
    int j8 = (o & 31) * 8;
    const float* qp = Qf + ((long)b * HH + hb * 32 + hh) * LQ + j8;
    float4 v0 = ((const float4*)qp)[0], v1 = ((const float4*)qp)[1];
    float4 m0 = make_float4(v0.x * qms[j8], v0.y * qms[j8 + 1],
                            v0.z * qms[j8 + 2], v0.w * qms[j8 + 3]);
    float4 m1 = make_float4(v1.x * qms[j8 + 4], v1.y * qms[j8 + 5],
                            v1.z * qms[j8 + 6], v1.w * qms[j8 + 7]);
    short8v hi, lo;
    split8(m0, m1, hi, lo);
    long qb = ((long)b * HH + hb * 32 + hh) * (2 * LQ) + j8;
    FragU fh, fl; fh.h = hi; fl.h = lo;
    *(uint4*)&Qs[qb] = fh.u;
    *(uint4*)&Qs[qb + LQ] = fl.u;
  }
}

// g1: S (3-term split MFMA, in-register) -> row softmax stats -> X bf16 + mr + 1/lr + Kmax
__global__ __launch_bounds__(256) void g1_SX(const void* Cp, const void* qmaskp,
                                             float* ws, const int* flag) {
  if (*flag != 0) return;
  __shared__ __align__(16) unsigned short CaH[64 * 40];  // [i][h] pitch 40 u16
  __shared__ __align__(16) unsigned short CaL[64 * 40];
  __shared__ float redm[64][4];
  __shared__ float redl[64][4];
  int t = threadIdx.x, b = blockIdx.y, i0 = blockIdx.x * 64;
  int w = t >> 6, l = t & 63;
  int lane_m = l & 15, kb = l >> 4;
  const float* Cf = (const float*)Cp;
  const unsigned short* Bf = (const unsigned short*)(ws + GOFF_BF);
  long cbase = (long)b * HH * LC;
  f32x4 z4 = {0.f, 0.f, 0.f, 0.f};
  f32x4 acc[4][4];
#pragma unroll
  for (int mf = 0; mf < 4; mf++)
#pragma unroll
    for (int nf = 0; nf < 4; nf++) acc[mf][nf] = z4;

  for (int hc = 0; hc < 8; hc++) {
    int h0 = hc * 32;
    __syncthreads();
#pragma unroll
    for (int hp = 0; hp < 4; hp++) {   // transpose-stage + split C tile [64 i][32 h]
      int hh = hp * 8 + (t >> 5);
      int ii = (t & 31) * 2;
      float2 cw = *(const float2*)&Cf[cbase + (long)(h0 + hh) * LC + i0 + ii];
      unsigned short xh, xl;
      split1(cw.x, xh, xl);
      CaH[ii * 40 + hh] = xh; CaL[ii * 40 + hh] = xl;
      split1(cw.y, xh, xl);
      CaH[(ii + 1) * 40 + hh] = xh; CaL[(ii + 1) * 40 + hh] = xl;
    }
    __syncthreads();
    short8v aH[4], aL[4];
#pragma unroll
    for (int mf = 0; mf < 4; mf++) {
      aH[mf] = ldfrag(&CaH[(mf * 16 + lane_m) * 40 + kb * 8]);
      aL[mf] = ldfrag(&CaL[(mf * 16 + lane_m) * 40 + kb * 8]);
    }
#pragma unroll
    for (int nf = 0; nf < 4; nf++) {
      long jb = ((long)b * LQ + w * 64 + nf * 16 + lane_m) * (2 * HH) + h0 + kb * 8;
      short8v bh = ldfrag(&Bf[jb]);
      short8v bl = ldfrag(&Bf[jb + HH]);
#pragma unroll
      for (int mf = 0; mf < 4; mf++) {
        acc[mf][nf] = MFMA(aH[mf], bh, acc[mf][nf]);
        acc[mf][nf] = MFMA(aH[mf], bl, acc[mf][nf]);
        acc[mf][nf] = MFMA(aL[mf], bh, acc[mf][nf]);
      }
    }
  }
  // ---- epilogue: row softmax stats + X store ----
  const float* q2g = ws + GOFF_Q2 + (long)b * LQ;
  const float* qmf = (const float*)qmaskp;
  float q2v[4], qm0v[4];
#pragma unroll
  for (int nf = 0; nf < 4; nf++) {
    int j = w * 64 + nf * 16 + lane_m;
    q2v[nf] = q2g[j];
    qm0v[nf] = (qmf[(long)b * LQ + j] != 0.f) ? 0.f : 1.f;
  }
  // pass 1: masked row max (16-lane groups share kb)
#pragma unroll
  for (int mf = 0; mf < 4; mf++)
#pragma unroll
    for (int r = 0; r < 4; r++) {
      float vx = -INFINITY;
#pragma unroll
      for (int nf = 0; nf < 4; nf++) {
        float s = acc[mf][nf][r] + q2v[nf];
        vx = fmaxf(vx, (qm0v[nf] != 0.f) ? s : NEGV);
      }
      vx = fmaxf(vx, __shfl_xor(vx, 1));
      vx = fmaxf(vx, __shfl_xor(vx, 2));
      vx = fmaxf(vx, __shfl_xor(vx, 4));
      vx = fmaxf(vx, __shfl_xor(vx, 8));
      if (lane_m == 0) redm[mf * 16 + kb * 4 + r][w] = vx;
    }
  __syncthreads();
  // pass 2: X = exp(S - mr), lr from rounded X
  unsigned short* Xu = (unsigned short*)(ws + GOFF_X);
#pragma unroll
  for (int mf = 0; mf < 4; mf++)
#pragma unroll
    for (int r = 0; r < 4; r++) {
      int il = mf * 16 + kb * 4 + r;
      float mr = fmaxf(fmaxf(fmaxf(redm[il][0], redm[il][1]),
                             fmaxf(redm[il][2], redm[il][3])), -60.f);
      float ls = 0.f;
#pragma unroll
      for (int nf = 0; nf < 4; nf++) {
        int j = w * 64 + nf * 16 + lane_m;
        float s = acc[mf][nf][r] + q2v[nf];
        unsigned short xb = f2bf(__expf(s - mr));
        Xu[((long)b * LC + i0 + il) * LQ + j] = xb;
        ls += qm0v[nf] * bf2f(xb);
      }
      ls += __shfl_xor(ls, 1);
      ls += __shfl_xor(ls, 2);
      ls += __shfl_xor(ls, 4);
      ls += __shfl_xor(ls, 8);
      if (lane_m == 0) redl[il][w] = ls;
    }
  __syncthreads();
  if (t < 64) {
    int il = t;
    float mrf = fmaxf(fmaxf(fmaxf(redm[il][0], redm[il][1]),
                            fmaxf(redm[il][2], redm[il][3])), -60.f);
    float lrf = redl[il][0] + redl[il][1] + redl[il][2] + redl[il][3];
    ws[GOFF_MR + (long)b * LC + i0 + il] = mrf;
    ws[GOFF_LR + (long)b * LC + i0 + il] = 1.0f / lrf;
    redm[il][0] = mrf;
  }
  __syncthreads();
  if (t == 0) {
    float km = -INFINITY;
    for (int i2 = 0; i2 < 64; i2++) km = fmaxf(km, redm[i2][0]);
    atomicMax((unsigned int*)(ws + GOFF_K) + b, fenc(km));
  }
}

// g2: T'[h,j] = qm0[j]/Lc[j] * sum_i (cm0[i]*exp(mr[i]-K)*X[i,j]) * C[h,i]; split hi/lo store
__global__ __launch_bounds__(1024) void g2_T(const void* Cp, const void* cmaskp, const void* qmaskp,
                                             float* ws, const int* flag) {
  if (*flag != 0) return;
  __shared__ __align__(16) unsigned short Pt[128 * 72];   // [jloc][i] pitch 72 u16
  __shared__ float lcred[128][9];
  __shared__ float lcinv[128];
  int t = threadIdx.x, b = blockIdx.y;
  int jb = blockIdx.x & 1, hb = blockIdx.x >> 1;
  int j0 = jb * 128, h0 = hb * 128;
  int w = t >> 6, l = t & 63;
  int lane_m = l & 15, kb = l >> 4;
  int wh = w & 7, wj = w >> 3;
  int jloc = t & 127, ib = t >> 7;   // stage mapping: 8 i per thread
  unsigned int Ke = ((unsigned int*)(ws + GOFF_K))[b];
  float Kf = fdec(Ke);
  const float* Cf = (const float*)Cp;
  const float* cmf = (const float*)cmaskp;
  const unsigned short* Xu = (const unsigned short*)(ws + GOFF_X);
  const float* mrp = ws + GOFF_MR + (long)b * LC;
  long cbase = (long)b * HH * LC;
  f32x4 z4 = {0.f, 0.f, 0.f, 0.f};
  f32x4 acc[4];
#pragma unroll
  for (int nf = 0; nf < 4; nf++) acc[nf] = z4;
  float lcp = 0.f;

  for (int ic = 0; ic < 32; ic++) {
    int i0 = ic * 64;
    __syncthreads();
    unsigned int pw[4];
#pragma unroll
    for (int e2 = 0; e2 < 4; e2++) {
      unsigned short s0, s1;
      {
        int i = i0 + ib * 8 + 2 * e2;
        float ecm = (cmf[(long)b * LC + i] != 0.f) ? 0.f : __expf(mrp[i] - Kf);
        float n = bf2f(Xu[((long)b * LC + i) * LQ + j0 + jloc]) * ecm;
        s0 = f2bf(n); lcp += n;
      }
      {
        int i = i0 + ib * 8 + 2 * e2 + 1;
        float ecm = (cmf[(long)b * LC + i] != 0.f) ? 0.f : __expf(mrp[i] - Kf);
        float n = bf2f(Xu[((long)b * LC + i) * LQ + j0 + jloc]) * ecm;
        s1 = f2bf(n); lcp += n;
      }
      pw[e2] = (unsigned int)s0 | ((unsigned int)s1 << 16);
    }
    *(uint4*)&Pt[jloc * 72 + ib * 8] = make_uint4(pw[0], pw[1], pw[2], pw[3]);
    __syncthreads();
#pragma unroll
    for (int ks = 0; ks < 2; ks++) {
      const float* cp = Cf + cbase + (long)(h0 + wh * 16 + lane_m) * LC + i0 + ks * 32 + kb * 8;
      short8v aH, aL;
      split8(((const float4*)cp)[0], ((const float4*)cp)[1], aH, aL);
#pragma unroll
      for (int nf = 0; nf < 4; nf++) {
        short8v bfr = ldfrag(&Pt[(wj * 64 + nf * 16 + lane_m) * 72 + ks * 32 + kb * 8]);
        acc[nf] = MFMA(aH, bfr, acc[nf]);
        acc[nf] = MFMA(aL, bfr, acc[nf]);
      }
    }
  }
  __syncthreads();
  lcred[jloc][ib] = lcp;
  __syncthreads();
  if (t < 128) {
    float s = 0.f;
    for (int q = 0; q < 8; q++) s += lcred[t][q];
    lcinv[t] = 1.0f / s;
  }
  __syncthreads();
  const float* qmf = (const float*)qmaskp;
  unsigned short* Tu = (unsigned short*)(ws + GOFF_TS);
#pragma unroll
  for (int nf = 0; nf < 4; nf++) {
    int jl = wj * 64 + nf * 16 + lane_m;
    int j = j0 + jl;
    float sc = lcinv[jl] * ((qmf[(long)b * LQ + j] != 0.f) ? 0.f : 1.f);
#pragma unroll
    for (int r = 0; r < 4; r++) {
      int h = h0 + wh * 16 + kb * 4 + r;
      float tv = acc[nf][r] * sc;
      unsigned short th, tl;
      split1(tv, th, tl);
      long tb2 = ((long)b * HH + h) * (2 * LQ);
      Tu[tb2 + j] = th;
      Tu[tb2 + LQ + j] = tl;
    }
  }
}

// g3: pure GEMM, no LDS/barriers. A1 = QS (pre-split), A2 = TS (pre-split), B = X (bf16).
//     A = (1/lr[i]) * X @ Q'^T ; Bt = (1/lr[i]) * X @ T'^T ; fused 4-plane output.
__global__ __launch_bounds__(512) void g3_out(const void* Cp, float* ws, void* outp,
                                              const int* flag) {
  if (*flag != 0) return;
  int t = threadIdx.x, b = blockIdx.y, i0 = blockIdx.x * 64;
  int w = t >> 6, l = t & 63;
  int lane_m = l & 15, kb = l >> 4;
  int hw2 = w * 32;
  const unsigned short* Xu = (const unsigned short*)(ws + GOFF_X);
  const unsigned short* Qs = (const unsigned short*)(ws + GOFF_QS);
  const unsigned short* Ts = (const unsigned short*)(ws + GOFF_TS);
  f32x4 z4 = {0.f, 0.f, 0.f, 0.f};
  f32x4 acc1[2][4], acc2[2][4];
#pragma unroll
  for (int mf = 0; mf < 2; mf++)
#pragma unroll
    for (int nf = 0; nf < 4; nf++) { acc1[mf][nf] = z4; acc2[mf][nf] = z4; }
#pragma unroll
  for (int kc = 0; kc < 8; kc++) {
    short8v bfr[4];
#pragma unroll
    for (int nf = 0; nf < 4; nf++)
      bfr[nf] = ldfrag(&Xu[((long)b * LC + i0 + nf * 16 + lane_m) * LQ + kc * 32 + kb * 8]);
#pragma unroll
    for (int mf = 0; mf < 2; mf++) {
      long ab = ((long)b * HH + hw2 + mf * 16 + lane_m) * (2 * LQ) + kc * 32 + kb * 8;
      short8v a1H = ldfrag(&Qs[ab]);
      short8v a1L = ldfrag(&Qs[ab + LQ]);
      short8v a2H = ldfrag(&Ts[ab]);
      short8v a2L = ldfrag(&Ts[ab + LQ]);
#pragma unroll
      for (int nf = 0; nf < 4; nf++) {
        acc1[mf][nf] = MFMA(a1H, bfr[nf], acc1[mf][nf]);
        acc1[mf][nf] = MFMA(a1L, bfr[nf], acc1[mf][nf]);
        acc2[mf][nf] = MFMA(a2H, bfr[nf], acc2[mf][nf]);
        acc2[mf][nf] = MFMA(a2L, bfr[nf], acc2[mf][nf]);
      }
    }
  }
  const float* Cf = (const float*)Cp;
  const float* lrp = ws + GOFF_LR + (long)b * LC;
  float linv[4];
#pragma unroll
  for (int nf = 0; nf < 4; nf++) linv[nf] = lrp[i0 + nf * 16 + lane_m];
  float* o = (float*)outp;
  long ob = (long)b * (4 * HH) * LC;
#pragma unroll
  for (int mf = 0; mf < 2; mf++)
#pragma unroll
    for (int nf = 0; nf < 4; nf++) {
      int i = i0 + nf * 16 + lane_m;
#pragma unroll
      for (int r = 0; r < 4; r++) {
        int h = hw2 + mf * 16 + kb * 4 + r;
        float cc = Cf[((long)b * HH + h) * LC + i];
        float av = acc1[mf][nf][r] * linv[nf];
        float bv = acc2[mf][nf][r] * linv[nf];
        long r0 = ob + (long)h * LC + i;
        o[r0] = cc;
        o[r0 + (long)HH * LC] = av;
        o[r0 + 2L * HH * LC] = cc * av;
        o[r0 + 3L * HH * LC] = cc * bv;
      }
    }
}

// =====================================================================
// ==================== bf16 MFMA pipeline (MODE 1) ====================
// =====================================================================

__global__ __launch_bounds__(256) void nk0_bfold(const void* Qp, const void* lpp,
                                                 float* ws, const int* flag) {
  if (*flag != 1) return;
  __shared__ __align__(16) unsigned short Qs[64 * 72];
  __shared__ float w1s[HH], w2s[HH], w3s[HH];
  __shared__ float q2red[4][64];
  int t = threadIdx.x;
  int b = blockIdx.y, j0 = blockIdx.x * 64;
  w1s[t] = ld<1>(lpp, t);
  w2s[t] = ld<1>(lpp, HH + t);
  w3s[t] = ld<1>(lpp, 2 * HH + t);
  const unsigned short* Qu = (const unsigned short*)Qp;
  long qbase = (long)b * HH * LQ;
  unsigned short* Bf = (unsigned short*)(ws + NOFF_BF);
  int jl = t & 63, hg = t >> 6;
  float q2a = 0.f;
  for (int hp = 0; hp < 4; hp++) {
    int h0 = hp * 64;
    __syncthreads();
    {
      int row = t >> 2, c = t & 3;
      const uint4* src = (const uint4*)&Qu[qbase + (long)(h0 + row) * LQ + j0 + c * 16];
      uint4 v0 = src[0]; uint4 v1 = src[1];
      *(uint4*)&Qs[row * 72 + c * 16] = v0;
      *(uint4*)&Qs[row * 72 + c * 16 + 8] = v1;
    }
    __syncthreads();
    unsigned int hiw[8], low[8];
#pragma unroll
    for (int e = 0; e < 16; e++) {
      int hh = hg * 16 + e;
      int h = h0 + hh;
      float qv = bf2f(Qs[hh * 72 + jl]);
      float bb = w1s[h] + w3s[h] * qv;
      q2a += w2s[h] * qv;
      unsigned short bh = f2bf(bb);
      float res = bb - bf2f(bh);
      unsigned short bl = f2bf(res);
      if (e & 1) { hiw[e >> 1] |= ((unsigned int)bh) << 16; low[e >> 1] |= ((unsigned int)bl) << 16; }
      else       { hiw[e >> 1] = bh; low[e >> 1] = bl; }
    }
    long bfb = ((long)b * LQ + j0 + jl) * (2 * HH);
    *(uint4*)&Bf[bfb + h0 + hg * 16]      = make_uint4(hiw[0], hiw[1], hiw[2], hiw[3]);
    *(uint4*)&Bf[bfb + h0 + hg * 16 + 8]  = make_uint4(hiw[4], hiw[5], hiw[6], hiw[7]);
    *(uint4*)&Bf[bfb + HH + h0 + hg * 16]     = make_uint4(low[0], low[1], low[2], low[3]);
    *(uint4*)&Bf[bfb + HH + h0 + hg * 16 + 8] = make_uint4(low[4], low[5], low[6], low[7]);
  }
  q2red[hg][jl] = q2a;
  __syncthreads();
  if (t < 64)
    ws[NOFF_Q2 + (long)b * LQ + j0 + t] =
        q2red[0][t] + q2red[1][t] + q2red[2][t] + q2red[3][t];
}

__global__ __launch_bounds__(256) void nk1_S(const void* Cp, float* ws, const int* flag) {
  if (*flag != 1) return;
  __shared__ __align__(16) unsigned short Ca[64 * 40];
  int t = threadIdx.x;
  int b = blockIdx.y, i0 = blockIdx.x * 64;
  int w = t >> 6, l = t & 63;
  int lane_m = l & 15, kb = l >> 4;
  const unsigned short* Cu = (const unsigned short*)Cp;
  const unsigned short* Bf = (const unsigned short*)(ws + NOFF_BF);
  long cbase = (long)b * HH * LC;
  f32x4 z4 = {0.f, 0.f, 0.f, 0.f};
  f32x4 acc[4][4];
#pragma unroll
  for (int mf = 0; mf < 4; mf++)
#pragma unroll
    for (int nf = 0; nf < 4; nf++) acc[mf][nf] = z4;

  for (int hc = 0; hc < 8; hc++) {
    int h0 = hc * 32;
    __syncthreads();
#pragma unroll
    for (int hp = 0; hp < 4; hp++) {
      int hh = hp * 8 + (t >> 5);
      int ii = (t & 31) * 2;
      unsigned int cw = *(const unsigned int*)&Cu[cbase + (long)(h0 + hh) * LC + i0 + ii];
      Ca[ii * 40 + hh] = (unsigned short)(cw & 0xffffu);
      Ca[(ii + 1) * 40 + hh] = (unsigned short)(cw >> 16);
    }
    __syncthreads();
    short8v afr[4];
#pragma unroll
    for (int mf = 0; mf < 4; mf++)
      afr[mf] = ldfrag(&Ca[(mf * 16 + lane_m) * 40 + kb * 8]);
#pragma unroll
    for (int nf = 0; nf < 4; nf++) {
      long jb = ((long)b * LQ + w * 64 + nf * 16 + lane_m) * (2 * HH) + h0 + kb * 8;
      short8v bh = ldfrag(&Bf[jb]);
      short8v bl = ldfrag(&Bf[jb + HH]);
#pragma unroll
      for (int mf = 0; mf < 4; mf++) {
        acc[mf][nf] = MFMA(afr[mf], bh, acc[mf][nf]);
        acc[mf][nf] = MFMA(afr[mf], bl, acc[mf][nf]);
      }
    }
  }
  const float* q2g = ws + NOFF_Q2 + (long)b * LQ;
#pragma unroll
  for (int nf = 0; nf < 4; nf++) {
    int j = w * 64 + nf * 16 + lane_m;
    float q2v = q2g[j];
    float* So = ws + OFF_S + ((long)b * LC + i0 + kb * 4) * LQ + j;
#pragma unroll
    for (int mf = 0; mf < 4; mf++)
#pragma unroll
      for (int r = 0; r < 4; r++)
        So[(long)(mf * 16 + r) * LQ] = acc[mf][nf][r] + q2v;
  }
}

__global__ __launch_bounds__(256) void nk2a_col(const void* cmaskp, float* ws, const int* flag) {
  if (*flag != 1) return;
  __shared__ float cms[128];
  int t = threadIdx.x, ch = blockIdx.x, b = blockIdx.y;
  int ib = ch * 128;
  if (t < 128) cms[t] = ld<1>(cmaskp, (long)b * LC + ib + t);
  __syncthreads();
  const float* Sb = ws + OFF_S + ((long)b * LC + ib) * LQ + t;
  float m = -INFINITY;
#pragma unroll 8
  for (int i = 0; i < 128; i++) {
    float v = (cms[i] != 0.f) ? NEGV : Sb[(long)i * LQ];
    m = fmaxf(m, v);
  }
  float s = 0.f;
#pragma unroll 8
  for (int i = 0; i < 128; i++) {
    float v = (cms[i] != 0.f) ? NEGV : Sb[(long)i * LQ];
    s += __expf(v - m);
  }
  ws[NOFF_PM + ((long)b * 16 + ch) * LQ + t] = m;
  ws[NOFF_PL + ((long)b * 16 + ch) * LQ + t] = s;
}

__global__ __launch_bounds__(512) void nk2b_T(const void* Cp, const void* cmaskp,
                                              float* ws, const int* flag) {
  if (*flag != 1) return;
  __shared__ __align__(16) unsigned short Pt[64 * 72];
  int t = threadIdx.x, b = blockIdx.y, j0 = blockIdx.x * 64;
  int w = t >> 6, l = t & 63;
  int lane_m = l & 15, kb = l >> 4;
  int jj = j0 + l;
  float M = -INFINITY;
#pragma unroll
  for (int c = 0; c < 16; c++)
    M = fmaxf(M, ws[NOFF_PM + ((long)b * 16 + c) * LQ + jj]);
  float L = 0.f;
#pragma unroll
  for (int c = 0; c < 16; c++)
    L += ws[NOFF_PL + ((long)b * 16 + c) * LQ + jj] *
         __expf(ws[NOFF_PM + ((long)b * 16 + c) * LQ + jj] - M);
  float Li = 1.0f / L;
  int hw = (w >> 1) * 64, jw = (w & 1) * 32;
  const unsigned short* Cu = (const unsigned short*)Cp;
  long cbase = (long)b * HH * LC;
  const float* Sb = ws + OFF_S + (long)b * LC * LQ;
  f32x4 z4 = {0.f, 0.f, 0.f, 0.f};
  f32x4 acc[4][2];
#pragma unroll
  for (int mf = 0; mf < 4; mf++) { acc[mf][0] = z4; acc[mf][1] = z4; }

  for (int ic = 0; ic < 32; ic++) {
    int i0 = ic * 64;
    __syncthreads();
    unsigned int pw[4];
#pragma unroll
    for (int s2 = 0; s2 < 4; s2++) {
      unsigned int lo16, hi16;
      {
        int i = i0 + w * 8 + 2 * s2;
        float cm = ld<1>(cmaskp, (long)b * LC + i);
        float sv = Sb[(long)i * LQ + jj];
        float p = (cm != 0.f) ? 0.f : __expf(sv - M) * Li;
        lo16 = f2bf(p);
      }
      {
        int i = i0 + w * 8 + 2 * s2 + 1;
        float cm = ld<1>(cmaskp, (long)b * LC + i);
        float sv = Sb[(long)i * LQ + jj];
        float p = (cm != 0.f) ? 0.f : __expf(sv - M) * Li;
        hi16 = f2bf(p);
      }
      pw[s2] = lo16 | (hi16 << 16);
    }
    *(uint4*)&Pt[l * 72 + w * 8] = make_uint4(pw[0], pw[1], pw[2], pw[3]);
    __syncthreads();
#pragma unroll
    for (int ks = 0; ks < 2; ks++) {
      short8v b0 = ldfrag(&Pt[(jw + lane_m) * 72 + ks * 32 + kb * 8]);
      short8v b1 = ldfrag(&Pt[(jw + 16 + lane_m) * 72 + ks * 32 + kb * 8]);
#pragma unroll
      for (int mf = 0; mf < 4; mf++) {
        short8v a = ldfrag(&Cu[cbase + (long)(hw + mf * 16 + lane_m) * LC + i0 + ks * 32 + kb * 8]);
        acc[mf][0] = MFMA(a, b0, acc[mf][0]);
        acc[mf][1] = MFMA(a, b1, acc[mf][1]);
      }
    }
  }
  unsigned short* Tt = (unsigned short*)(ws + NOFF_T);
#pragma unroll
  for (int mf = 0; mf < 4; mf++)
#pragma unroll
    for (int nf = 0; nf < 2; nf++)
#pragma unroll
      for (int r = 0; r < 4; r++) {
        int h = hw + mf * 16 + kb * 4 + r;
        int j = j0 + jw + nf * 16 + lane_m;
        Tt[((long)b * HH + h) * LQ + j] = f2bf(acc[mf][nf][r]);
      }
}

__global__ __launch_bounds__(512) void nk3_out(const void* Cp, const void* Qp, const void* qmaskp,
                                               float* ws, void* outp, const int* flag) {
  if (*flag != 1) return;
  __shared__ __align__(16) unsigned short Pr[64 * 264];
  __shared__ float qms[LQ];
  int t = threadIdx.x, b = blockIdx.y, i0 = blockIdx.x * 64;
  int w = t >> 6, l = t & 63;
  if (t < LQ) qms[t] = ld<1>(qmaskp, (long)b * LQ + t);
  __syncthreads();
  const float* Sb = ws + OFF_S + ((long)b * LC + i0) * LQ;
#pragma unroll
  for (int r = 0; r < 8; r++) {
    int row = w * 8 + r;
    float v[4];
#pragma unroll
    for (int c = 0; c < 4; c++) {
      float sv = Sb[(long)row * LQ + l + 64 * c];
      v[c] = (qms[l + 64 * c] != 0.f) ? NEGV : sv;
    }
    float mx = fmaxf(fmaxf(v[0], v[1]), fmaxf(v[2], v[3]));
#pragma unroll
    for (int o = 1; o < 64; o <<= 1) mx = fmaxf(mx, __shfl_xor(mx, o));
    float e[4]; float sm = 0.f;
#pragma unroll
    for (int c = 0; c < 4; c++) { e[c] = __expf(v[c] - mx); sm += e[c]; }
#pragma unroll
    for (int o = 1; o < 64; o <<= 1) sm += __shfl_xor(sm, o);
    float inv = 1.0f / sm;
#pragma unroll
    for (int c = 0; c < 4; c++) Pr[row * 264 + l + 64 * c] = f2bf(e[c] * inv);
  }
  __syncthreads();
  int lane_m = l & 15, kb = l >> 4;
  int hw2 = (w >> 1) * 64, iw = (w & 1) * 32;
  const unsigned short* Qu = (const unsigned short*)Qp;
  const unsigned short* Tt = (const unsigned short*)(ws + NOFF_T);
  long qrow = (long)b * HH * LQ;
  f32x4 z4 = {0.f, 0.f, 0.f, 0.f};
  f32x4 acc1[4][2], acc2[4][2];
#pragma unroll
  for (int mf = 0; mf < 4; mf++) {
    acc1[mf][0] = z4; acc1[mf][1] = z4;
    acc2[mf][0] = z4; acc2[mf][1] = z4;
  }
#pragma unroll
  for (int kc = 0; kc < 8; kc++) {
    short8v b0 = ldfrag(&Pr[(iw + lane_m) * 264 + kc * 32 + kb * 8]);
    short8v b1 = ldfrag(&Pr[(iw + 16 + lane_m) * 264 + kc * 32 + kb * 8]);
#pragma unroll
    for (int mf = 0; mf < 4; mf++) {
      long ro = qrow + (long)(hw2 + mf * 16 + lane_m) * LQ + kc * 32 + kb * 8;
      short8v a1 = ldfrag(&Qu[ro]);
      acc1[mf][0] = MFMA(a1, b0, acc1[mf][0]);
      acc1[mf][1] = MFMA(a1, b1, acc1[mf][1]);
      short8v a2 = ldfrag(&Tt[ro]);
      acc2[mf][0] = MFMA(a2, b0, acc2[mf][0]);
      acc2[mf][1] = MFMA(a2, b1, acc2[mf][1]);
    }
  }
  unsigned short* o = (unsigned short*)outp;
  const unsigned short* Cu = (const unsigned short*)Cp;
  long ob = (long)b * (4 * HH) * LC;
#pragma unroll
  for (int mf = 0; mf < 4; mf++)
#pragma unroll
    for (int nf = 0; nf < 2; nf++) {
      int i = i0 + iw + nf * 16 + lane_m;
#pragma unroll
      for (int r = 0; r < 4; r++) {
        int h = hw2 + mf * 16 + kb * 4 + r;
        unsigned short craw = Cu[(long)(b * HH + h) * LC + i];
        float cc = bf2f(craw);
        float av = acc1[mf][nf][r], bv = acc2[mf][nf][r];
        long r0 = ob + (long)h * LC + i;
        o[r0] = craw;
        o[r0 + (long)HH * LC] = f2bf(av);
        o[r0 + 2L * HH * LC] = f2bf(cc * av);
        o[r0 + 3L * HH * LC] = f2bf(cc * bv);
      }
    }
}

extern "C" void kernel_launch(void* const* d_in, const int* in_sizes, int n_in,
                              void* d_out, int out_size, void* d_ws, size_t ws_size,
                              hipStream_t stream) {
  const void* C  = d_in[0];
  const void* Q  = d_in[1];
  const void* cm = d_in[2];
  const void* qm = d_in[3];
  const void* lp = d_in[4];
  float* ws = (float*)d_ws;
  int* flag = (int*)(ws + OFF_FLAG);
  unsigned int* kz = (unsigned int*)(ws + GOFF_K);

  sniff_kernel<<<1, 64, 0, stream>>>((const unsigned int*)C, flag, kz);

  // ---- MODE 0: fp32 I/O split-bf16 MFMA pipeline (X-factorized softmax) ----
  f0_bfold<<<dim3(4, BB), 256, 0, stream>>>(Q, lp, ws, flag);
  g0b_Qsplit<<<dim3(8, BB), 256, 0, stream>>>(Q, qm, ws, flag);
  g1_SX<<<dim3(LC / 64, BB), 256, 0, stream>>>(C, qm, ws, flag);
  g2_T<<<dim3(4, BB), 1024, 0, stream>>>(C, cm, qm, ws, flag);
  g3_out<<<dim3(LC / 64, BB), 512, 0, stream>>>(C, ws, d_out, flag);

  // ---- MODE 1: bf16 I/O MFMA pipeline ----
  nk0_bfold<<<dim3(4, BB), 256, 0, stream>>>(Q, lp, ws, flag);
  nk1_S<<<dim3(LC / 64, BB), 256, 0, stream>>>(C, ws, flag);
  nk2a_col<<<dim3(16, BB), 256, 0, stream>>>(cm, ws, flag);
  nk2b_T<<<dim3(4, BB), 512, 0, stream>>>(C, cm, ws, flag);
  nk3_out<<<dim3(LC / 64, BB), 512, 0, stream>>>(C, Q, qm, ws, d_out, flag);
}